// Round 8
// baseline (464.016 us; speedup 1.0000x reference)
//
#include <hip/hip_runtime.h>
#include <math.h>

#define N_NODES 100000
#define N_EDGES 1600000
#define N_GRAPHS 128
#define IN_DIM 329
#define NH 4
#define CC 64
#define HC 256
#define NEG_SLOPE 0.2f
#define LOG2E 1.44269504f

#define K_PAD 384            // 6 * 64
#define M_PAD 100096         // 1564 * 64
#define XBYTES (N_NODES * IN_DIM * 4)   // 131,600,000
#define NBUCK 196            // buckets of 512 nodes
#define BCAP 10240           // bucket capacity (expected 8673, +16 sigma)
#define EPB 8192             // edges per bin2 block

typedef unsigned short u16;
typedef unsigned char u8;
typedef unsigned int u32;
typedef __attribute__((ext_vector_type(8))) short short8;   // 8 bf16 (4 VGPRs)
typedef __attribute__((ext_vector_type(4))) float floatx4;
typedef __attribute__((ext_vector_type(2))) float floatx2;

__device__ __forceinline__ u16 f2bf(float f) {
    u32 u = __float_as_uint(f);
    u32 r = (u + 0x7FFFu + ((u >> 16) & 1u)) >> 16;   // RNE
    return (u16)r;
}

// pack two f32 -> two bf16 (truncation) in one v_perm_b32
__device__ __forceinline__ u32 pkbf(float a, float b) {
    return __builtin_amdgcn_perm(__float_as_uint(b), __float_as_uint(a), 0x07060302u);
}

// ---- fp8 e4m3 (OCP) helpers: HW path via cvt builtins, SW fallback --------
__device__ __forceinline__ u8 f2fp8(float f) {
#if __has_builtin(__builtin_amdgcn_cvt_pk_fp8_f32)
    int pk = __builtin_amdgcn_cvt_pk_fp8_f32(f, f, 0, false);
    return (u8)(pk & 0xFF);
#else
    u32 u = __float_as_uint(f);
    u32 sgn = (u >> 24) & 0x80;
    float af = fabsf(f);
    if (af >= 448.f) return (u8)(sgn | 0x7E);
    if (af < 0.015625f) {
        int m = (int)rintf(af * 512.f);
        if (m >= 8) return (u8)(sgn | 0x08);
        return (u8)(sgn | (u32)m);
    }
    u32 au = u & 0x7FFFFFFF;
    u32 r = au + 0x0007FFFFu + ((au >> 20) & 1u);
    u32 e = r >> 23;
    u32 m3 = (r >> 20) & 7;
    int fe = (int)e - 127 + 7;
    if (fe >= 16) return (u8)(sgn | 0x7E);
    return (u8)(sgn | ((u32)fe << 3) | m3);
#endif
}

__device__ __forceinline__ float fp82f_sw(u32 b) {
    u32 s = (b & 0x80u) << 24;
    u32 e = (b >> 3) & 0xF;
    u32 m = b & 7;
    if (e == 0) {
        float v = (float)m * 0.001953125f;
        return (b & 0x80) ? -v : v;
    }
    return __uint_as_float(s | ((e + 120) << 23) | (m << 20));
}

__device__ __forceinline__ floatx4 dec4(int p) {
#if __has_builtin(__builtin_amdgcn_cvt_pk_f32_fp8)
    floatx2 lo = __builtin_amdgcn_cvt_pk_f32_fp8(p, false);
    floatx2 hi = __builtin_amdgcn_cvt_pk_f32_fp8(p, true);
    floatx4 r; r.x = lo.x; r.y = lo.y; r.z = hi.x; r.w = hi.y;
    return r;
#else
    floatx4 r;
    r.x = fp82f_sw(p & 0xFF);  r.y = fp82f_sw((p >> 8) & 0xFF);
    r.z = fp82f_sw((p >> 16) & 0xFF); r.w = fp82f_sw((p >> 24) & 0xFF);
    return r;
#endif
}

__device__ __forceinline__ void async_copy16(const void* g, void* l) {
    __builtin_amdgcn_global_load_lds((const __attribute__((address_space(1))) void*)g,
                                     (__attribute__((address_space(3))) void*)l, 16, 0, 0);
}

// ---------------------------------------------------------------------------
// Tiny convert: W (fp32 [329][256]) -> WbT (bf16 [256][K_PAD], transposed)
// ---------------------------------------------------------------------------
__global__ __launch_bounds__(256) void convw_kernel(const float* __restrict__ W, u16* __restrict__ WbT)
{
    int i = blockIdx.x * 256 + threadIdx.x;
    if (i >= HC * 96) return;
    int c = i / 96;
    int k0 = (i - c * 96) * 4;
    ushort4 o = {0, 0, 0, 0};
    const float* wp = W + c;
    if (k0 < IN_DIM)     o.x = f2bf(wp[(size_t)k0 * HC]);
    if (k0 + 1 < IN_DIM) o.y = f2bf(wp[(size_t)(k0 + 1) * HC]);
    if (k0 + 2 < IN_DIM) o.z = f2bf(wp[(size_t)(k0 + 2) * HC]);
    if (k0 + 3 < IN_DIM) o.w = f2bf(wp[(size_t)(k0 + 3) * HC]);
    *(ushort4*)(WbT + (size_t)c * K_PAD + k0) = o;
}

// ---------------------------------------------------------------------------
// MFMA GEMM v7: v6 structure (64x256 tile, 8 waves 2x4, 48 KB LDS,
// 3 blocks/CU) + FUSED a_src/a_dst epilogue. Each col-wave owns exactly one
// head (64 cols), so a[n,h] = sum_c acc*att is a per-wave reduce: 64 fmaf +
// 4 shfl_xor rounds in 16-lane groups; lr==0 lanes store. Kills the a8
// kernel and its 25.6 MB xp8 re-read; computed from f32 acc (more accurate
// than the old fp8 path).
// ---------------------------------------------------------------------------
__global__ __launch_bounds__(512, 6) void gemm_mfma_kernel(
    const float* __restrict__ x, const u16* __restrict__ WbT, u8* __restrict__ xp8,
    const float* __restrict__ att_src, const float* __restrict__ att_dst,
    float* __restrict__ a_src, float* __restrict__ a_dst)
{
    __shared__ __align__(16) float Asf[64 * 64];   // 16 KB fp32, 16-chunk XOR swizzled rows
    __shared__ __align__(16) u16   Bs[256 * 64];   // 32 KB bf16, 128B rows, 8-chunk XOR

    const int tid = threadIdx.x;
    const int lane = tid & 63;
    const int wave = tid >> 6;            // 0..7
    const int lr = lane & 15;
    const int q = lane >> 4;
    const int row0 = blockIdx.x * 64;
    const int rm0 = (wave & 1) * 32;      // row offset within tile (0/32)
    const int cn0 = (wave >> 1) * 64;     // col offset within tile (0/64/128/192)

    floatx4 acc[2][4];
#pragma unroll
    for (int i = 0; i < 2; i++)
#pragma unroll
        for (int j = 0; j < 4; j++) {
            acc[i][j].x = 0.f; acc[i][j].y = 0.f; acc[i][j].z = 0.f; acc[i][j].w = 0.f;
        }

    for (int k0 = 0; k0 < K_PAD; k0 += 64) {
        // stage A: 64 rows x 64 fp32 = 16 KB = 1024 chunks of 16B, 2/thread.
        // physical chunk p at row r holds logical chunk (p ^ (r&15)).
#pragma unroll
        for (int t = 0; t < 2; t++) {
            int chunk = tid + t * 512;
            int row = chunk >> 4, ch = chunk & 15;
            int chl = ch ^ (row & 15);
            long gb = (long)(row0 + row) * (IN_DIM * 4) + (long)k0 * 4 + chl * 16;
            if (gb > (long)XBYTES - 16) gb = (long)XBYTES - 16;   // OOB rows never stored
            async_copy16((const char*)x + gb, (char*)Asf + (size_t)chunk * 16);
        }
        // stage B: 256 cols x 64 k bf16 = 32 KB = 2048 chunks, 4/thread
#pragma unroll
        for (int t = 0; t < 4; t++) {
            int off = (tid + t * 512) * 16;
            int rowb = off >> 7;          // col index 0..255
            int colb = off & 127;         // byte within 128B row
            int gcol = colb ^ ((rowb & 7) * 16);
            const char* gb = (const char*)WbT + (size_t)rowb * (K_PAD * 2) + k0 * 2 + gcol;
            async_copy16(gb, (char*)Bs + off);
        }
        asm volatile("s_waitcnt vmcnt(0)" ::: "memory");
        __syncthreads();

        // compute (R0-proven fragment paths, wave-tile 32x64)
#pragma unroll
        for (int ks = 0; ks < 2; ks++) {
            short8 af[2], bf[4];
#pragma unroll
            for (int i = 0; i < 2; i++) {
                int ra = rm0 + i * 16 + lr;
                int c0 = ks * 8 + q * 2;
                int sw = ra & 15;
                const float4* base = (const float4*)(Asf + ra * 64);
                float4 lo = base[c0 ^ sw];
                float4 hi = base[(c0 ^ sw) ^ 1];          // (c0+1)^sw == (c0^sw)^1 (c0 even)
                union { short8 v; u32 w[4]; } fr;
                fr.w[0] = pkbf(lo.x, lo.y);
                fr.w[1] = pkbf(lo.z, lo.w);
                fr.w[2] = pkbf(hi.x, hi.y);
                fr.w[3] = pkbf(hi.z, hi.w);
                af[i] = fr.v;
            }
#pragma unroll
            for (int j = 0; j < 4; j++) {
                int rb = cn0 + j * 16 + lr;
                int cb = (ks * 64 + q * 16) ^ ((rb & 7) * 16);
                bf[j] = *(const short8*)((const char*)Bs + rb * 128 + cb);
            }
#pragma unroll
            for (int i = 0; i < 2; i++)
#pragma unroll
                for (int j = 0; j < 4; j++)
                    acc[i][j] = __builtin_amdgcn_mfma_f32_16x16x32_bf16(af[i], bf[j], acc[i][j], 0, 0, 0);
        }
        __syncthreads();
    }

    // epilogue 1: fp8 store (C/D layout: col=lane&15 block, row=q*4+reg)
#pragma unroll
    for (int i = 0; i < 2; i++) {
#pragma unroll
        for (int j = 0; j < 4; j++) {
            int col = cn0 + j * 16 + lr;
            float v[4] = {acc[i][j].x, acc[i][j].y, acc[i][j].z, acc[i][j].w};
#pragma unroll
            for (int r = 0; r < 4; r++) {
                int row = row0 + rm0 + i * 16 + q * 4 + r;
                if (row < N_NODES) xp8[(size_t)row * HC + col] = f2fp8(v[r]);
            }
        }
    }

    // epilogue 2: fused a_src/a_dst. This wave's 64 cols = head (wave>>1).
    // as[j]/ad[j] = att weight for col cn0+j*16+lr (att layout [H][64] linear).
    float as0 = att_src[cn0 + 0 * 16 + lr], ad0 = att_dst[cn0 + 0 * 16 + lr];
    float as1 = att_src[cn0 + 1 * 16 + lr], ad1 = att_dst[cn0 + 1 * 16 + lr];
    float as2 = att_src[cn0 + 2 * 16 + lr], ad2 = att_dst[cn0 + 2 * 16 + lr];
    float as3 = att_src[cn0 + 3 * 16 + lr], ad3 = att_dst[cn0 + 3 * 16 + lr];

    float ps[2][4], pd[2][4];
#pragma unroll
    for (int i = 0; i < 2; i++) {
        ps[i][0] = acc[i][0].x * as0 + acc[i][1].x * as1 + acc[i][2].x * as2 + acc[i][3].x * as3;
        ps[i][1] = acc[i][0].y * as0 + acc[i][1].y * as1 + acc[i][2].y * as2 + acc[i][3].y * as3;
        ps[i][2] = acc[i][0].z * as0 + acc[i][1].z * as1 + acc[i][2].z * as2 + acc[i][3].z * as3;
        ps[i][3] = acc[i][0].w * as0 + acc[i][1].w * as1 + acc[i][2].w * as2 + acc[i][3].w * as3;
        pd[i][0] = acc[i][0].x * ad0 + acc[i][1].x * ad1 + acc[i][2].x * ad2 + acc[i][3].x * ad3;
        pd[i][1] = acc[i][0].y * ad0 + acc[i][1].y * ad1 + acc[i][2].y * ad2 + acc[i][3].y * ad3;
        pd[i][2] = acc[i][0].z * ad0 + acc[i][1].z * ad1 + acc[i][2].z * ad2 + acc[i][3].z * ad3;
        pd[i][3] = acc[i][0].w * ad0 + acc[i][1].w * ad1 + acc[i][2].w * ad2 + acc[i][3].w * ad3;
    }
    // reduce over the 16-lane lr group (stays within the group for m<16)
#pragma unroll
    for (int m = 1; m < 16; m <<= 1) {
#pragma unroll
        for (int i = 0; i < 2; i++) {
#pragma unroll
            for (int r = 0; r < 4; r++) {
                ps[i][r] += __shfl_xor(ps[i][r], m, 64);
                pd[i][r] += __shfl_xor(pd[i][r], m, 64);
            }
        }
    }
    if (lr == 0) {
        int head = wave >> 1;
#pragma unroll
        for (int i = 0; i < 2; i++) {
#pragma unroll
            for (int r = 0; r < 4; r++) {
                int row = row0 + rm0 + i * 16 + q * 4 + r;
                if (row < N_NODES) {
                    a_src[row * 4 + head] = ps[i][r] * LOG2E;
                    a_dst[row * 4 + head] = pd[i][r] * LOG2E;
                }
            }
        }
    }
}

// ---------------------------------------------------------------------------
// Pass 1: bucket-bin edges. Block-local reservation (gpos) keeps each run's
// lines written by one block/XCD -> L2 write-combining works (R5/R6 lesson).
// ---------------------------------------------------------------------------
__global__ __launch_bounds__(256) void bin2_kernel(
    const int* __restrict__ ei, int* __restrict__ bcur, int2* __restrict__ bins)
{
    __shared__ int hist[NBUCK];
    __shared__ int gpos[NBUCK];
    __shared__ int lcur[NBUCK];
    __shared__ int sc[256];

    const int t = threadIdx.x;
    const int lo = blockIdx.x * EPB;
    const int hi = min(lo + EPB, N_EDGES + N_NODES);

    for (int b = t; b < NBUCK; b += 256) hist[b] = 0;
    __syncthreads();

    for (int i = lo + t; i < hi; i += 256) {
        int d = (i < N_EDGES) ? ei[N_EDGES + i] : (i - N_EDGES);
        atomicAdd(&hist[d >> 9], 1);
    }
    __syncthreads();

    int v = (t < NBUCK) ? hist[t] : 0;
    if (t < NBUCK) { gpos[t] = atomicAdd(&bcur[t], v); lcur[t] = 0; }
    (void)sc;
    __syncthreads();

    for (int i = lo + t; i < hi; i += 256) {
        int s, d;
        if (i < N_EDGES) { s = ei[i]; d = ei[N_EDGES + i]; }
        else             { s = i - N_EDGES; d = s; }
        int b = d >> 9;
        int pos = gpos[b] + atomicAdd(&lcur[b], 1);
        if (pos < BCAP) {
            int2 r; r.x = s; r.y = d;
            bins[(size_t)b * BCAP + pos] = r;
        }
    }
}

// ---------------------------------------------------------------------------
// Pass 2: one 512-thread block per bucket. LDS counting sort -> compact CSR.
// ---------------------------------------------------------------------------
__global__ __launch_bounds__(512) void fill3_kernel(
    const int* __restrict__ bcur, const int2* __restrict__ bins,
    int2* __restrict__ rs_deg, int* __restrict__ csr)
{
    __shared__ int deg[512];
    __shared__ int cur[512];
    __shared__ int sc[256];
    __shared__ int order[BCAP];

    const int t = threadIdx.x;
    const int b = blockIdx.x;
    const int cnt = min(bcur[b], BCAP);
    const int2* bp = bins + (size_t)b * BCAP;
    const int gbase = b * BCAP;

    deg[t] = 0;
    __syncthreads();
    for (int i = t; i < cnt; i += 512) atomicAdd(&deg[bp[i].y & 511], 1);
    __syncthreads();

    int d0 = 0, d1 = 0;
    if (t < 256) {
        d0 = deg[2 * t]; d1 = deg[2 * t + 1];
        sc[t] = d0 + d1;
    }
    __syncthreads();
    for (int off = 1; off < 256; off <<= 1) {
        int u = (t < 256 && t >= off) ? sc[t - off] : 0;
        __syncthreads();
        if (t < 256) sc[t] += u;
        __syncthreads();
    }
    if (t < 256) {
        int excl = sc[t] - (d0 + d1);
        cur[2 * t] = excl;
        cur[2 * t + 1] = excl + d0;
        int n0 = b * 512 + 2 * t;
        if (n0 < N_NODES)     { int2 rd; rd.x = gbase + excl;      rd.y = d0; rs_deg[n0] = rd; }
        if (n0 + 1 < N_NODES) { int2 rd; rd.x = gbase + excl + d0; rd.y = d1; rs_deg[n0 + 1] = rd; }
    }
    __syncthreads();

    for (int i = t; i < cnt; i += 512) {
        int2 r = bp[i];
        int pos = atomicAdd(&cur[r.y & 511], 1);
        order[pos] = r.x;
    }
    __syncthreads();

    for (int i = t; i < cnt; i += 512) csr[gbase + i] = order[i];
}

// ---------------------------------------------------------------------------
// Fused single-pass segment softmax + fp8 aggregation + head-mean + bias/relu
// + FUSED global mean-pool (was pool1): block-level LDS reduction when all 4
// nodes share a graph (common: runs avg 781 nodes), per-wave global atomics
// at graph boundaries. hbuf (25.6 MB write + 25.6 MB read) eliminated.
// ---------------------------------------------------------------------------
__global__ __launch_bounds__(256) void aggregate_kernel(
    const u8* __restrict__ xp8, const float* __restrict__ a_src, const float* __restrict__ a_dst,
    const int2* __restrict__ rs_deg, const int* __restrict__ csr,
    const float* __restrict__ bias, const int* __restrict__ batch,
    float* __restrict__ gsum, int* __restrict__ gcnt)
{
    __shared__ float gacc[64];
    __shared__ int gids[4];

    int w = threadIdx.x >> 6;
    int n = blockIdx.x * 4 + w;
    int lane = threadIdx.x & 63;
    // grid is exactly N_NODES/4 blocks: n always < N_NODES, no early return
    int2 rd = rs_deg[n];
    int rstart = __builtin_amdgcn_readfirstlane(rd.x);
    int deg    = __builtin_amdgcn_readfirstlane(rd.y);
    const int* ep = csr + rstart;
    int h = lane >> 4;
    int xoff = lane * 4;

    float ad = a_dst[n * 4 + h];

    const int dm1 = deg - 1;          // deg >= 1 (self-loop)
    const int nb  = (deg + 3) >> 2;

    float acc0 = 0.f, acc1 = 0.f, acc2 = 0.f, acc3 = 0.f, den = 0.f;

    // pipeline state
    int iA0, iA1, iA2, iA3;                       // idx, even-slot batches (SGPR)
    int iB0 = 0, iB1 = 0, iB2 = 0, iB3 = 0;       // idx, odd-slot batches (SGPR)
    float aa0, aa1, aa2, aa3;  int pa0, pa1, pa2, pa3;   // data buffer A
    float ab0, ab1, ab2, ab3;  int pb0, pb1, pb2, pb3;   // data buffer B

#define AGG_LDI(eb_, j0, j1, j2, j3) do { \
        j0 = ep[min((eb_), dm1)];     j1 = ep[min((eb_) + 1, dm1)]; \
        j2 = ep[min((eb_) + 2, dm1)]; j3 = ep[min((eb_) + 3, dm1)]; } while (0)

#define AGG_LDD(j0, j1, j2, j3, a0_, a1_, a2_, a3_, q0_, q1_, q2_, q3_) do { \
        a0_ = a_src[(size_t)(j0) * 4 + h];  q0_ = *(const int*)(xp8 + (size_t)(j0) * HC + xoff); \
        a1_ = a_src[(size_t)(j1) * 4 + h];  q1_ = *(const int*)(xp8 + (size_t)(j1) * HC + xoff); \
        a2_ = a_src[(size_t)(j2) * 4 + h];  q2_ = *(const int*)(xp8 + (size_t)(j2) * HC + xoff); \
        a3_ = a_src[(size_t)(j3) * 4 + h];  q3_ = *(const int*)(xp8 + (size_t)(j3) * HC + xoff); } while (0)

#define AGG_CMP(eb_, a0_, a1_, a2_, a3_, q0_, q1_, q2_, q3_) do { \
        float z0 = a0_ + ad, z1 = a1_ + ad, z2 = a2_ + ad, z3 = a3_ + ad; \
        float w0 = exp2f(fmaxf(z0, NEG_SLOPE * z0)); \
        float w1 = exp2f(fmaxf(z1, NEG_SLOPE * z1)); \
        float w2 = exp2f(fmaxf(z2, NEG_SLOPE * z2)); \
        float w3 = exp2f(fmaxf(z3, NEG_SLOPE * z3)); \
        if ((eb_) + 3 >= deg) {               /* wave-uniform, taken only on last batch */ \
            if ((eb_) + 1 >= deg) w1 = 0.f; \
            if ((eb_) + 2 >= deg) w2 = 0.f; \
            if ((eb_) + 3 >= deg) w3 = 0.f; \
        } \
        den += (w0 + w1) + (w2 + w3); \
        floatx4 v0 = dec4(q0_), v1 = dec4(q1_), v2 = dec4(q2_), v3 = dec4(q3_); \
        acc0 = fmaf(w0, v0.x, acc0); acc1 = fmaf(w0, v0.y, acc1); \
        acc2 = fmaf(w0, v0.z, acc2); acc3 = fmaf(w0, v0.w, acc3); \
        acc0 = fmaf(w1, v1.x, acc0); acc1 = fmaf(w1, v1.y, acc1); \
        acc2 = fmaf(w1, v1.z, acc2); acc3 = fmaf(w1, v1.w, acc3); \
        acc0 = fmaf(w2, v2.x, acc0); acc1 = fmaf(w2, v2.y, acc1); \
        acc2 = fmaf(w2, v2.z, acc2); acc3 = fmaf(w2, v2.w, acc3); \
        acc0 = fmaf(w3, v3.x, acc0); acc1 = fmaf(w3, v3.y, acc1); \
        acc2 = fmaf(w3, v3.z, acc2); acc3 = fmaf(w3, v3.w, acc3); } while (0)

    // prologue: batch 0 idx + data, batch 1 idx
    AGG_LDI(0, iA0, iA1, iA2, iA3);
    AGG_LDD(iA0, iA1, iA2, iA3, aa0, aa1, aa2, aa3, pa0, pa1, pa2, pa3);
    if (nb > 1) AGG_LDI(4, iB0, iB1, iB2, iB3);

    for (int b = 0; b < nb; b += 2) {
        int eb = b * 4;
        // even slot: data(b+1)->bufB first (its idx is old), then idx(b+2)->iA
        if (b + 1 < nb) AGG_LDD(iB0, iB1, iB2, iB3, ab0, ab1, ab2, ab3, pb0, pb1, pb2, pb3);
        if (b + 2 < nb) AGG_LDI(eb + 8, iA0, iA1, iA2, iA3);
        AGG_CMP(eb, aa0, aa1, aa2, aa3, pa0, pa1, pa2, pa3);
        if (b + 1 < nb) {
            // odd slot
            if (b + 2 < nb) AGG_LDD(iA0, iA1, iA2, iA3, aa0, aa1, aa2, aa3, pa0, pa1, pa2, pa3);
            if (b + 3 < nb) AGG_LDI(eb + 12, iB0, iB1, iB2, iB3);
            AGG_CMP(eb + 4, ab0, ab1, ab2, ab3, pb0, pb1, pb2, pb3);
        }
    }

#undef AGG_LDI
#undef AGG_LDD
#undef AGG_CMP

    float r = 1.f / den;
    acc0 *= r; acc1 *= r; acc2 *= r; acc3 *= r;
#pragma unroll
    for (int m = 16; m <= 32; m <<= 1) {
        acc0 += __shfl_xor(acc0, m, 64);
        acc1 += __shfl_xor(acc1, m, 64);
        acc2 += __shfl_xor(acc2, m, 64);
        acc3 += __shfl_xor(acc3, m, 64);
    }

    // fused pooling epilogue
    int g = batch[n];
    if (threadIdx.x < 64) gacc[threadIdx.x] = 0.f;
    if (lane == 0) gids[w] = g;
    __syncthreads();
    bool uni = (gids[0] == gids[1]) && (gids[1] == gids[2]) && (gids[2] == gids[3]);

    if (lane < 16) {
        const float* bp = bias + lane * 4;
        float o0 = fmaxf(0.25f * acc0 + bp[0], 0.f);
        float o1 = fmaxf(0.25f * acc1 + bp[1], 0.f);
        float o2 = fmaxf(0.25f * acc2 + bp[2], 0.f);
        float o3 = fmaxf(0.25f * acc3 + bp[3], 0.f);
        if (uni) {
            atomicAdd(&gacc[lane * 4 + 0], o0);
            atomicAdd(&gacc[lane * 4 + 1], o1);
            atomicAdd(&gacc[lane * 4 + 2], o2);
            atomicAdd(&gacc[lane * 4 + 3], o3);
        } else {
            float* gp = gsum + (size_t)g * 64 + lane * 4;
            atomicAdd(gp + 0, o0);
            atomicAdd(gp + 1, o1);
            atomicAdd(gp + 2, o2);
            atomicAdd(gp + 3, o3);
            if (lane == 0) atomicAdd(&gcnt[g], 1);
        }
    }
    __syncthreads();
    if (uni) {
        if (threadIdx.x < 64) atomicAdd(&gsum[(size_t)gids[0] * 64 + threadIdx.x], gacc[threadIdx.x]);
        if (threadIdx.x == 0) atomicAdd(&gcnt[gids[0]], 4);
    }
}

// Pool pass 2: per-graph MLP head.
__global__ __launch_bounds__(64) void pool2_kernel(
    const float* __restrict__ gsum, const int* __restrict__ gcnt,
    const float* __restrict__ w1, const float* __restrict__ b1,
    const float* __restrict__ w2, const float* __restrict__ b2,
    float* __restrict__ out)
{
    int g = blockIdx.x;
    int lane = threadIdx.x;
    __shared__ float gv[64];
    gv[lane] = gsum[g * 64 + lane] / (float)max(gcnt[g], 1);
    __syncthreads();
    float hid = b1[lane];
    for (int c = 0; c < 64; c++) hid = fmaf(gv[c], w1[c * 64 + lane], hid);
    hid = fmaxf(hid, 0.f);
    float part = hid * w2[lane];
#pragma unroll
    for (int off = 32; off > 0; off >>= 1) part += __shfl_xor(part, off, 64);
    if (lane == 0) out[g] = 1.f / (1.f + __expf(-(part + b2[0])));
}

// ---------------------------------------------------------------------------
extern "C" void kernel_launch(void* const* d_in, const int* in_sizes, int n_in,
                              void* d_out, int out_size, void* d_ws, size_t ws_size,
                              hipStream_t stream)
{
    const float* x       = (const float*)d_in[0];
    const float* W       = (const float*)d_in[1];
    const float* att_src = (const float*)d_in[2];
    const float* att_dst = (const float*)d_in[3];
    const float* bias    = (const float*)d_in[4];
    const float* w1      = (const float*)d_in[5];
    const float* b1      = (const float*)d_in[6];
    const float* w2      = (const float*)d_in[7];
    const float* b2      = (const float*)d_in[8];
    const int*   ei      = (const int*)d_in[9];
    const int*   batch   = (const int*)d_in[10];
    float* out = (float*)d_out;

    char* ws = (char*)d_ws;
    size_t off = 0;
    auto alloc = [&](size_t bytes) -> void* {
        void* p = ws + off;
        off += (bytes + 255) & ~(size_t)255;
        return p;
    };
    u16*   WbT       = (u16*)alloc((size_t)HC * K_PAD * 2);             // 196 KB
    u8*    xp8       = (u8*)alloc((size_t)N_NODES * HC);                // 25.6 MB
    float* a_src_b   = (float*)alloc((size_t)N_NODES * NH * 4);
    float* a_dst_b   = (float*)alloc((size_t)N_NODES * NH * 4);
    size_t zoff0 = off;
    int*   bcur      = (int*)alloc((size_t)NBUCK * 4);                  // zeroed
    float* gsum      = (float*)alloc((size_t)N_GRAPHS * 64 * 4);        // zeroed
    int*   gcnt      = (int*)alloc((size_t)N_GRAPHS * 4);               // zeroed
    size_t zbytes = off - zoff0;
    int2*  bins      = (int2*)alloc((size_t)NBUCK * BCAP * 8);          // 16.1 MB
    int2*  rs_deg    = (int2*)alloc((size_t)N_NODES * 8);               // 800 KB
    int*   csr       = (int*)alloc((size_t)NBUCK * BCAP * 4);           // 8 MB

    hipMemsetAsync(bcur, 0, zbytes, stream);

    convw_kernel<<<(HC * 96 + 255) / 256, 256, 0, stream>>>(W, WbT);

    gemm_mfma_kernel<<<M_PAD / 64, 512, 0, stream>>>(x, WbT, xp8, att_src, att_dst,
                                                     a_src_b, a_dst_b);

    int tot = N_EDGES + N_NODES;
    bin2_kernel<<<(tot + EPB - 1) / EPB, 256, 0, stream>>>(ei, bcur, bins);
    fill3_kernel<<<NBUCK, 512, 0, stream>>>(bcur, bins, rs_deg, csr);

    aggregate_kernel<<<N_NODES / 4, 256, 0, stream>>>(xp8, a_src_b, a_dst_b,
                                                      rs_deg, csr, bias, batch,
                                                      gsum, gcnt);

    pool2_kernel<<<N_GRAPHS, 64, 0, stream>>>(gsum, gcnt, w1, b1, w2, b2, out);
}

// Round 9
// 384.033 us; speedup vs baseline: 1.2083x; 1.2083x over previous
//
#include <hip/hip_runtime.h>
#include <math.h>

#define N_NODES 100000
#define N_EDGES 1600000
#define N_GRAPHS 128
#define IN_DIM 329
#define NH 4
#define CC 64
#define HC 256
#define NEG_SLOPE 0.2f
#define LOG2E 1.44269504f

#define K_PAD 384            // 6 * 64
#define M_PAD 100096         // 1564 * 64
#define XBYTES (N_NODES * IN_DIM * 4)   // 131,600,000
#define NBUCK 196            // buckets of 512 nodes
#define BCAP 10240           // bucket capacity (expected 8673, +16 sigma)
#define EPB 8192             // edges per bin2 block
#define BIN_BLOCKS 208       // ceil((N_EDGES+N_NODES)/EPB)
#define GEMM_BLOCKS (M_PAD / 64)

typedef unsigned short u16;
typedef unsigned char u8;
typedef unsigned int u32;
typedef __attribute__((ext_vector_type(8))) short short8;   // 8 bf16 (4 VGPRs)
typedef __attribute__((ext_vector_type(4))) float floatx4;
typedef __attribute__((ext_vector_type(2))) float floatx2;

__device__ __forceinline__ u16 f2bf(float f) {
    u32 u = __float_as_uint(f);
    u32 r = (u + 0x7FFFu + ((u >> 16) & 1u)) >> 16;   // RNE
    return (u16)r;
}

// pack two f32 -> two bf16 (truncation) in one v_perm_b32
__device__ __forceinline__ u32 pkbf(float a, float b) {
    return __builtin_amdgcn_perm(__float_as_uint(b), __float_as_uint(a), 0x07060302u);
}

// ---- fp8 e4m3 (OCP) helpers: HW path via cvt builtins, SW fallback --------
__device__ __forceinline__ u8 f2fp8(float f) {
#if __has_builtin(__builtin_amdgcn_cvt_pk_fp8_f32)
    int pk = __builtin_amdgcn_cvt_pk_fp8_f32(f, f, 0, false);
    return (u8)(pk & 0xFF);
#else
    u32 u = __float_as_uint(f);
    u32 sgn = (u >> 24) & 0x80;
    float af = fabsf(f);
    if (af >= 448.f) return (u8)(sgn | 0x7E);
    if (af < 0.015625f) {
        int m = (int)rintf(af * 512.f);
        if (m >= 8) return (u8)(sgn | 0x08);
        return (u8)(sgn | (u32)m);
    }
    u32 au = u & 0x7FFFFFFF;
    u32 r = au + 0x0007FFFFu + ((au >> 20) & 1u);
    u32 e = r >> 23;
    u32 m3 = (r >> 20) & 7;
    int fe = (int)e - 127 + 7;
    if (fe >= 16) return (u8)(sgn | 0x7E);
    return (u8)(sgn | ((u32)fe << 3) | m3);
#endif
}

__device__ __forceinline__ float fp82f_sw(u32 b) {
    u32 s = (b & 0x80u) << 24;
    u32 e = (b >> 3) & 0xF;
    u32 m = b & 7;
    if (e == 0) {
        float v = (float)m * 0.001953125f;
        return (b & 0x80) ? -v : v;
    }
    return __uint_as_float(s | ((e + 120) << 23) | (m << 20));
}

__device__ __forceinline__ floatx4 dec4(int p) {
#if __has_builtin(__builtin_amdgcn_cvt_pk_f32_fp8)
    floatx2 lo = __builtin_amdgcn_cvt_pk_f32_fp8(p, false);
    floatx2 hi = __builtin_amdgcn_cvt_pk_f32_fp8(p, true);
    floatx4 r; r.x = lo.x; r.y = lo.y; r.z = hi.x; r.w = hi.y;
    return r;
#else
    floatx4 r;
    r.x = fp82f_sw(p & 0xFF);  r.y = fp82f_sw((p >> 8) & 0xFF);
    r.z = fp82f_sw((p >> 16) & 0xFF); r.w = fp82f_sw((p >> 24) & 0xFF);
    return r;
#endif
}

__device__ __forceinline__ void async_copy16(const void* g, void* l) {
    __builtin_amdgcn_global_load_lds((const __attribute__((address_space(1))) void*)g,
                                     (__attribute__((address_space(3))) void*)l, 16, 0, 0);
}

// ---------------------------------------------------------------------------
// Tiny convert: W (fp32 [329][256]) -> WbT (bf16 [256][K_PAD], transposed)
// ---------------------------------------------------------------------------
__global__ __launch_bounds__(256) void convw_kernel(const float* __restrict__ W, u16* __restrict__ WbT)
{
    int i = blockIdx.x * 256 + threadIdx.x;
    if (i >= HC * 96) return;
    int c = i / 96;
    int k0 = (i - c * 96) * 4;
    ushort4 o = {0, 0, 0, 0};
    const float* wp = W + c;
    if (k0 < IN_DIM)     o.x = f2bf(wp[(size_t)k0 * HC]);
    if (k0 + 1 < IN_DIM) o.y = f2bf(wp[(size_t)(k0 + 1) * HC]);
    if (k0 + 2 < IN_DIM) o.z = f2bf(wp[(size_t)(k0 + 2) * HC]);
    if (k0 + 3 < IN_DIM) o.w = f2bf(wp[(size_t)(k0 + 3) * HC]);
    *(ushort4*)(WbT + (size_t)c * K_PAD + k0) = o;
}

// ---------------------------------------------------------------------------
// Fat kernel: blocks [0, BIN_BLOCKS) run the bin2 edge-bucketing body;
// blocks [BIN_BLOCKS, BIN_BLOCKS+GEMM_BLOCKS) run the v6 MFMA GEMM with
// fused a_src/a_dst epilogue. The two workloads are independent (ei vs x/W),
// previously serialized on the stream; merged, bin2 rides in the GEMM's
// scheduling shadow. LDS: 48K (gemm) + 2.4K (bin) = 50.6K -> 3 blocks/CU.
// ---------------------------------------------------------------------------
__global__ __launch_bounds__(512, 6) void gemm_bin_kernel(
    const float* __restrict__ x, const u16* __restrict__ WbT, u8* __restrict__ xp8,
    const float* __restrict__ att_src, const float* __restrict__ att_dst,
    float* __restrict__ a_src, float* __restrict__ a_dst,
    const int* __restrict__ ei, int* __restrict__ bcur, int2* __restrict__ bins)
{
    __shared__ __align__(16) float Asf[64 * 64];   // 16 KB fp32, 16-chunk XOR swizzled rows
    __shared__ __align__(16) u16   Bs[256 * 64];   // 32 KB bf16, 128B rows, 8-chunk XOR
    __shared__ int hist[NBUCK];
    __shared__ int gpos[NBUCK];
    __shared__ int lcur[NBUCK];

    const int tid = threadIdx.x;

    if (blockIdx.x < BIN_BLOCKS) {
        // ---------------- bin2 body (512 threads) ----------------
        const int lo = blockIdx.x * EPB;
        const int hi = min(lo + EPB, N_EDGES + N_NODES);

        for (int b = tid; b < NBUCK; b += 512) hist[b] = 0;
        __syncthreads();

        for (int i = lo + tid; i < hi; i += 512) {
            int d = (i < N_EDGES) ? ei[N_EDGES + i] : (i - N_EDGES);
            atomicAdd(&hist[d >> 9], 1);
        }
        __syncthreads();

        if (tid < NBUCK) {
            int v = hist[tid];
            gpos[tid] = atomicAdd(&bcur[tid], v);
            lcur[tid] = 0;
        }
        __syncthreads();

        for (int i = lo + tid; i < hi; i += 512) {
            int s, d;
            if (i < N_EDGES) { s = ei[i]; d = ei[N_EDGES + i]; }
            else             { s = i - N_EDGES; d = s; }
            int b = d >> 9;
            int pos = gpos[b] + atomicAdd(&lcur[b], 1);
            if (pos < BCAP) {
                int2 r; r.x = s; r.y = d;
                bins[(size_t)b * BCAP + pos] = r;
            }
        }
        return;
    }

    // ---------------- GEMM body (v6 structure + fused a epilogue) ----------
    const int lane = tid & 63;
    const int wave = tid >> 6;            // 0..7
    const int lr = lane & 15;
    const int q = lane >> 4;
    const int row0 = (blockIdx.x - BIN_BLOCKS) * 64;
    const int rm0 = (wave & 1) * 32;      // row offset within tile (0/32)
    const int cn0 = (wave >> 1) * 64;     // col offset within tile (0/64/128/192)

    floatx4 acc[2][4];
#pragma unroll
    for (int i = 0; i < 2; i++)
#pragma unroll
        for (int j = 0; j < 4; j++) {
            acc[i][j].x = 0.f; acc[i][j].y = 0.f; acc[i][j].z = 0.f; acc[i][j].w = 0.f;
        }

    for (int k0 = 0; k0 < K_PAD; k0 += 64) {
        // stage A: 64 rows x 64 fp32 = 16 KB = 1024 chunks of 16B, 2/thread.
        // physical chunk p at row r holds logical chunk (p ^ (r&15)).
#pragma unroll
        for (int t = 0; t < 2; t++) {
            int chunk = tid + t * 512;
            int row = chunk >> 4, ch = chunk & 15;
            int chl = ch ^ (row & 15);
            long gb = (long)(row0 + row) * (IN_DIM * 4) + (long)k0 * 4 + chl * 16;
            if (gb > (long)XBYTES - 16) gb = (long)XBYTES - 16;   // OOB rows never stored
            async_copy16((const char*)x + gb, (char*)Asf + (size_t)chunk * 16);
        }
        // stage B: 256 cols x 64 k bf16 = 32 KB = 2048 chunks, 4/thread
#pragma unroll
        for (int t = 0; t < 4; t++) {
            int off = (tid + t * 512) * 16;
            int rowb = off >> 7;          // col index 0..255
            int colb = off & 127;         // byte within 128B row
            int gcol = colb ^ ((rowb & 7) * 16);
            const char* gb = (const char*)WbT + (size_t)rowb * (K_PAD * 2) + k0 * 2 + gcol;
            async_copy16(gb, (char*)Bs + off);
        }
        asm volatile("s_waitcnt vmcnt(0)" ::: "memory");
        __syncthreads();

        // compute (R0-proven fragment paths, wave-tile 32x64)
#pragma unroll
        for (int ks = 0; ks < 2; ks++) {
            short8 af[2], bf[4];
#pragma unroll
            for (int i = 0; i < 2; i++) {
                int ra = rm0 + i * 16 + lr;
                int c0 = ks * 8 + q * 2;
                int sw = ra & 15;
                const float4* base = (const float4*)(Asf + ra * 64);
                float4 lo = base[c0 ^ sw];
                float4 hi = base[(c0 ^ sw) ^ 1];          // (c0+1)^sw == (c0^sw)^1 (c0 even)
                union { short8 v; u32 w[4]; } fr;
                fr.w[0] = pkbf(lo.x, lo.y);
                fr.w[1] = pkbf(lo.z, lo.w);
                fr.w[2] = pkbf(hi.x, hi.y);
                fr.w[3] = pkbf(hi.z, hi.w);
                af[i] = fr.v;
            }
#pragma unroll
            for (int j = 0; j < 4; j++) {
                int rb = cn0 + j * 16 + lr;
                int cb = (ks * 64 + q * 16) ^ ((rb & 7) * 16);
                bf[j] = *(const short8*)((const char*)Bs + rb * 128 + cb);
            }
#pragma unroll
            for (int i = 0; i < 2; i++)
#pragma unroll
                for (int j = 0; j < 4; j++)
                    acc[i][j] = __builtin_amdgcn_mfma_f32_16x16x32_bf16(af[i], bf[j], acc[i][j], 0, 0, 0);
        }
        __syncthreads();
    }

    // epilogue 1: fp8 store (C/D layout: col=lane&15 block, row=q*4+reg)
#pragma unroll
    for (int i = 0; i < 2; i++) {
#pragma unroll
        for (int j = 0; j < 4; j++) {
            int col = cn0 + j * 16 + lr;
            float v[4] = {acc[i][j].x, acc[i][j].y, acc[i][j].z, acc[i][j].w};
#pragma unroll
            for (int r = 0; r < 4; r++) {
                int row = row0 + rm0 + i * 16 + q * 4 + r;
                if (row < N_NODES) xp8[(size_t)row * HC + col] = f2fp8(v[r]);
            }
        }
    }

    // epilogue 2: fused a_src/a_dst. This wave's 64 cols = head (wave>>1).
    float as0 = att_src[cn0 + 0 * 16 + lr], ad0 = att_dst[cn0 + 0 * 16 + lr];
    float as1 = att_src[cn0 + 1 * 16 + lr], ad1 = att_dst[cn0 + 1 * 16 + lr];
    float as2 = att_src[cn0 + 2 * 16 + lr], ad2 = att_dst[cn0 + 2 * 16 + lr];
    float as3 = att_src[cn0 + 3 * 16 + lr], ad3 = att_dst[cn0 + 3 * 16 + lr];

    float ps[2][4], pd[2][4];
#pragma unroll
    for (int i = 0; i < 2; i++) {
        ps[i][0] = acc[i][0].x * as0 + acc[i][1].x * as1 + acc[i][2].x * as2 + acc[i][3].x * as3;
        ps[i][1] = acc[i][0].y * as0 + acc[i][1].y * as1 + acc[i][2].y * as2 + acc[i][3].y * as3;
        ps[i][2] = acc[i][0].z * as0 + acc[i][1].z * as1 + acc[i][2].z * as2 + acc[i][3].z * as3;
        ps[i][3] = acc[i][0].w * as0 + acc[i][1].w * as1 + acc[i][2].w * as2 + acc[i][3].w * as3;
        pd[i][0] = acc[i][0].x * ad0 + acc[i][1].x * ad1 + acc[i][2].x * ad2 + acc[i][3].x * ad3;
        pd[i][1] = acc[i][0].y * ad0 + acc[i][1].y * ad1 + acc[i][2].y * ad2 + acc[i][3].y * ad3;
        pd[i][2] = acc[i][0].z * ad0 + acc[i][1].z * ad1 + acc[i][2].z * ad2 + acc[i][3].z * ad3;
        pd[i][3] = acc[i][0].w * ad0 + acc[i][1].w * ad1 + acc[i][2].w * ad2 + acc[i][3].w * ad3;
    }
#pragma unroll
    for (int m = 1; m < 16; m <<= 1) {
#pragma unroll
        for (int i = 0; i < 2; i++) {
#pragma unroll
            for (int r = 0; r < 4; r++) {
                ps[i][r] += __shfl_xor(ps[i][r], m, 64);
                pd[i][r] += __shfl_xor(pd[i][r], m, 64);
            }
        }
    }
    if (lr == 0) {
        int head = wave >> 1;
#pragma unroll
        for (int i = 0; i < 2; i++) {
#pragma unroll
            for (int r = 0; r < 4; r++) {
                int row = row0 + rm0 + i * 16 + q * 4 + r;
                if (row < N_NODES) {
                    a_src[row * 4 + head] = ps[i][r] * LOG2E;
                    a_dst[row * 4 + head] = pd[i][r] * LOG2E;
                }
            }
        }
    }
}

// ---------------------------------------------------------------------------
// Pass 2: one 512-thread block per bucket. LDS counting sort -> compact CSR.
// ---------------------------------------------------------------------------
__global__ __launch_bounds__(512) void fill3_kernel(
    const int* __restrict__ bcur, const int2* __restrict__ bins,
    int2* __restrict__ rs_deg, int* __restrict__ csr)
{
    __shared__ int deg[512];
    __shared__ int cur[512];
    __shared__ int sc[256];
    __shared__ int order[BCAP];

    const int t = threadIdx.x;
    const int b = blockIdx.x;
    const int cnt = min(bcur[b], BCAP);
    const int2* bp = bins + (size_t)b * BCAP;
    const int gbase = b * BCAP;

    deg[t] = 0;
    __syncthreads();
    for (int i = t; i < cnt; i += 512) atomicAdd(&deg[bp[i].y & 511], 1);
    __syncthreads();

    int d0 = 0, d1 = 0;
    if (t < 256) {
        d0 = deg[2 * t]; d1 = deg[2 * t + 1];
        sc[t] = d0 + d1;
    }
    __syncthreads();
    for (int off = 1; off < 256; off <<= 1) {
        int u = (t < 256 && t >= off) ? sc[t - off] : 0;
        __syncthreads();
        if (t < 256) sc[t] += u;
        __syncthreads();
    }
    if (t < 256) {
        int excl = sc[t] - (d0 + d1);
        cur[2 * t] = excl;
        cur[2 * t + 1] = excl + d0;
        int n0 = b * 512 + 2 * t;
        if (n0 < N_NODES)     { int2 rd; rd.x = gbase + excl;      rd.y = d0; rs_deg[n0] = rd; }
        if (n0 + 1 < N_NODES) { int2 rd; rd.x = gbase + excl + d0; rd.y = d1; rs_deg[n0 + 1] = rd; }
    }
    __syncthreads();

    for (int i = t; i < cnt; i += 512) {
        int2 r = bp[i];
        int pos = atomicAdd(&cur[r.y & 511], 1);
        order[pos] = r.x;
    }
    __syncthreads();

    for (int i = t; i < cnt; i += 512) csr[gbase + i] = order[i];
}

// ---------------------------------------------------------------------------
// Fused single-pass segment softmax + fp8 aggregation + head-mean + bias/relu.
// Software-pipelined gather loop (R1-proven form, no block barrier).
// ---------------------------------------------------------------------------
__global__ __launch_bounds__(256) void aggregate_kernel(
    const u8* __restrict__ xp8, const float* __restrict__ a_src, const float* __restrict__ a_dst,
    const int2* __restrict__ rs_deg, const int* __restrict__ csr,
    const float* __restrict__ bias, float* __restrict__ hbuf)
{
    int n = blockIdx.x * 4 + (threadIdx.x >> 6);
    int lane = threadIdx.x & 63;
    if (n >= N_NODES) return;
    int2 rd = rs_deg[n];
    int rstart = __builtin_amdgcn_readfirstlane(rd.x);
    int deg    = __builtin_amdgcn_readfirstlane(rd.y);
    const int* ep = csr + rstart;
    int h = lane >> 4;
    int xoff = lane * 4;

    float ad = a_dst[n * 4 + h];

    const int dm1 = deg - 1;          // deg >= 1 (self-loop)
    const int nb  = (deg + 3) >> 2;

    float acc0 = 0.f, acc1 = 0.f, acc2 = 0.f, acc3 = 0.f, den = 0.f;

    // pipeline state
    int iA0, iA1, iA2, iA3;                       // idx, even-slot batches (SGPR)
    int iB0 = 0, iB1 = 0, iB2 = 0, iB3 = 0;       // idx, odd-slot batches (SGPR)
    float aa0, aa1, aa2, aa3;  int pa0, pa1, pa2, pa3;   // data buffer A
    float ab0, ab1, ab2, ab3;  int pb0, pb1, pb2, pb3;   // data buffer B

#define AGG_LDI(eb_, j0, j1, j2, j3) do { \
        j0 = ep[min((eb_), dm1)];     j1 = ep[min((eb_) + 1, dm1)]; \
        j2 = ep[min((eb_) + 2, dm1)]; j3 = ep[min((eb_) + 3, dm1)]; } while (0)

#define AGG_LDD(j0, j1, j2, j3, a0_, a1_, a2_, a3_, q0_, q1_, q2_, q3_) do { \
        a0_ = a_src[(size_t)(j0) * 4 + h];  q0_ = *(const int*)(xp8 + (size_t)(j0) * HC + xoff); \
        a1_ = a_src[(size_t)(j1) * 4 + h];  q1_ = *(const int*)(xp8 + (size_t)(j1) * HC + xoff); \
        a2_ = a_src[(size_t)(j2) * 4 + h];  q2_ = *(const int*)(xp8 + (size_t)(j2) * HC + xoff); \
        a3_ = a_src[(size_t)(j3) * 4 + h];  q3_ = *(const int*)(xp8 + (size_t)(j3) * HC + xoff); } while (0)

#define AGG_CMP(eb_, a0_, a1_, a2_, a3_, q0_, q1_, q2_, q3_) do { \
        float z0 = a0_ + ad, z1 = a1_ + ad, z2 = a2_ + ad, z3 = a3_ + ad; \
        float w0 = exp2f(fmaxf(z0, NEG_SLOPE * z0)); \
        float w1 = exp2f(fmaxf(z1, NEG_SLOPE * z1)); \
        float w2 = exp2f(fmaxf(z2, NEG_SLOPE * z2)); \
        float w3 = exp2f(fmaxf(z3, NEG_SLOPE * z3)); \
        if ((eb_) + 3 >= deg) {               /* wave-uniform, taken only on last batch */ \
            if ((eb_) + 1 >= deg) w1 = 0.f; \
            if ((eb_) + 2 >= deg) w2 = 0.f; \
            if ((eb_) + 3 >= deg) w3 = 0.f; \
        } \
        den += (w0 + w1) + (w2 + w3); \
        floatx4 v0 = dec4(q0_), v1 = dec4(q1_), v2 = dec4(q2_), v3 = dec4(q3_); \
        acc0 = fmaf(w0, v0.x, acc0); acc1 = fmaf(w0, v0.y, acc1); \
        acc2 = fmaf(w0, v0.z, acc2); acc3 = fmaf(w0, v0.w, acc3); \
        acc0 = fmaf(w1, v1.x, acc0); acc1 = fmaf(w1, v1.y, acc1); \
        acc2 = fmaf(w1, v1.z, acc2); acc3 = fmaf(w1, v1.w, acc3); \
        acc0 = fmaf(w2, v2.x, acc0); acc1 = fmaf(w2, v2.y, acc1); \
        acc2 = fmaf(w2, v2.z, acc2); acc3 = fmaf(w2, v2.w, acc3); \
        acc0 = fmaf(w3, v3.x, acc0); acc1 = fmaf(w3, v3.y, acc1); \
        acc2 = fmaf(w3, v3.z, acc2); acc3 = fmaf(w3, v3.w, acc3); } while (0)

    // prologue: batch 0 idx + data, batch 1 idx
    AGG_LDI(0, iA0, iA1, iA2, iA3);
    AGG_LDD(iA0, iA1, iA2, iA3, aa0, aa1, aa2, aa3, pa0, pa1, pa2, pa3);
    if (nb > 1) AGG_LDI(4, iB0, iB1, iB2, iB3);

    for (int b = 0; b < nb; b += 2) {
        int eb = b * 4;
        // even slot: data(b+1)->bufB first (its idx is old), then idx(b+2)->iA
        if (b + 1 < nb) AGG_LDD(iB0, iB1, iB2, iB3, ab0, ab1, ab2, ab3, pb0, pb1, pb2, pb3);
        if (b + 2 < nb) AGG_LDI(eb + 8, iA0, iA1, iA2, iA3);
        AGG_CMP(eb, aa0, aa1, aa2, aa3, pa0, pa1, pa2, pa3);
        if (b + 1 < nb) {
            // odd slot
            if (b + 2 < nb) AGG_LDD(iA0, iA1, iA2, iA3, aa0, aa1, aa2, aa3, pa0, pa1, pa2, pa3);
            if (b + 3 < nb) AGG_LDI(eb + 12, iB0, iB1, iB2, iB3);
            AGG_CMP(eb + 4, ab0, ab1, ab2, ab3, pb0, pb1, pb2, pb3);
        }
    }

#undef AGG_LDI
#undef AGG_LDD
#undef AGG_CMP

    float r = 1.f / den;
    acc0 *= r; acc1 *= r; acc2 *= r; acc3 *= r;
#pragma unroll
    for (int m = 16; m <= 32; m <<= 1) {
        acc0 += __shfl_xor(acc0, m, 64);
        acc1 += __shfl_xor(acc1, m, 64);
        acc2 += __shfl_xor(acc2, m, 64);
        acc3 += __shfl_xor(acc3, m, 64);
    }
    if (lane < 16) {
        const float* bp = bias + lane * 4;
        float4 o;
        o.x = fmaxf(0.25f * acc0 + bp[0], 0.f);
        o.y = fmaxf(0.25f * acc1 + bp[1], 0.f);
        o.z = fmaxf(0.25f * acc2 + bp[2], 0.f);
        o.w = fmaxf(0.25f * acc3 + bp[3], 0.f);
        *(float4*)&hbuf[(size_t)n * CC + lane * 4] = o;
    }
}

// ---------------------------------------------------------------------------
// Pool pass 1: per-wave running sums over sorted batch, flush on boundary.
// ---------------------------------------------------------------------------
__global__ __launch_bounds__(256) void pool1_kernel(
    const float* __restrict__ hbuf, const int* __restrict__ batch,
    float* __restrict__ gsum, int* __restrict__ gcnt)
{
    int w = threadIdx.x >> 6, lane = threadIdx.x & 63;
    int r0 = blockIdx.x * 128 + w * 32;
    if (r0 >= N_NODES) return;
    int r1 = min(r0 + 32, N_NODES);
    int cur = batch[r0];
    float s = 0.f;
    int c = 0;
    for (int r = r0; r < r1; r++) {
        int bb = batch[r];
        if (bb != cur) {
            atomicAdd(&gsum[cur * 64 + lane], s);
            if (lane == 0) atomicAdd(&gcnt[cur], c);
            s = 0.f; c = 0; cur = bb;
        }
        s += hbuf[(size_t)r * CC + lane];
        c++;
    }
    atomicAdd(&gsum[cur * 64 + lane], s);
    if (lane == 0) atomicAdd(&gcnt[cur], c);
}

// Pool pass 2: per-graph MLP head.
__global__ __launch_bounds__(64) void pool2_kernel(
    const float* __restrict__ gsum, const int* __restrict__ gcnt,
    const float* __restrict__ w1, const float* __restrict__ b1,
    const float* __restrict__ w2, const float* __restrict__ b2,
    float* __restrict__ out)
{
    int g = blockIdx.x;
    int lane = threadIdx.x;
    __shared__ float gv[64];
    gv[lane] = gsum[g * 64 + lane] / (float)max(gcnt[g], 1);
    __syncthreads();
    float hid = b1[lane];
    for (int c = 0; c < 64; c++) hid = fmaf(gv[c], w1[c * 64 + lane], hid);
    hid = fmaxf(hid, 0.f);
    float part = hid * w2[lane];
#pragma unroll
    for (int off = 32; off > 0; off >>= 1) part += __shfl_xor(part, off, 64);
    if (lane == 0) out[g] = 1.f / (1.f + __expf(-(part + b2[0])));
}

// ---------------------------------------------------------------------------
extern "C" void kernel_launch(void* const* d_in, const int* in_sizes, int n_in,
                              void* d_out, int out_size, void* d_ws, size_t ws_size,
                              hipStream_t stream)
{
    const float* x       = (const float*)d_in[0];
    const float* W       = (const float*)d_in[1];
    const float* att_src = (const float*)d_in[2];
    const float* att_dst = (const float*)d_in[3];
    const float* bias    = (const float*)d_in[4];
    const float* w1      = (const float*)d_in[5];
    const float* b1      = (const float*)d_in[6];
    const float* w2      = (const float*)d_in[7];
    const float* b2      = (const float*)d_in[8];
    const int*   ei      = (const int*)d_in[9];
    const int*   batch   = (const int*)d_in[10];
    float* out = (float*)d_out;

    char* ws = (char*)d_ws;
    size_t off = 0;
    auto alloc = [&](size_t bytes) -> void* {
        void* p = ws + off;
        off += (bytes + 255) & ~(size_t)255;
        return p;
    };
    u16*   WbT       = (u16*)alloc((size_t)HC * K_PAD * 2);             // 196 KB
    u8*    xp8       = (u8*)alloc((size_t)N_NODES * HC);                // 25.6 MB
    float* a_src_b   = (float*)alloc((size_t)N_NODES * NH * 4);
    float* a_dst_b   = (float*)alloc((size_t)N_NODES * NH * 4);
    size_t zoff0 = off;
    int*   bcur      = (int*)alloc((size_t)NBUCK * 4);                  // zeroed
    float* gsum      = (float*)alloc((size_t)N_GRAPHS * 64 * 4);        // zeroed
    int*   gcnt      = (int*)alloc((size_t)N_GRAPHS * 4);               // zeroed
    size_t zbytes = off - zoff0;
    int2*  bins      = (int2*)alloc((size_t)NBUCK * BCAP * 8);          // 16.1 MB
    int2*  rs_deg    = (int2*)alloc((size_t)N_NODES * 8);               // 800 KB
    int*   csr       = (int*)alloc((size_t)NBUCK * BCAP * 4);           // 8 MB
    float* hbuf      = (float*)alloc((size_t)N_NODES * CC * 4);         // 25.6 MB

    hipMemsetAsync(bcur, 0, zbytes, stream);

    convw_kernel<<<(HC * 96 + 255) / 256, 256, 0, stream>>>(W, WbT);

    gemm_bin_kernel<<<BIN_BLOCKS + GEMM_BLOCKS, 512, 0, stream>>>(
        x, WbT, xp8, att_src, att_dst, a_src_b, a_dst_b, ei, bcur, bins);

    fill3_kernel<<<NBUCK, 512, 0, stream>>>(bcur, bins, rs_deg, csr);

    aggregate_kernel<<<(N_NODES + 3) / 4, 256, 0, stream>>>(xp8, a_src_b, a_dst_b,
                                                            rs_deg, csr, bias, hbuf);

    pool1_kernel<<<(N_NODES + 127) / 128, 256, 0, stream>>>(hbuf, batch, gsum, gcnt);
    pool2_kernel<<<N_GRAPHS, 64, 0, stream>>>(gsum, gcnt, w1, b1, w2, b2, out);
}

// Round 10
// 383.616 us; speedup vs baseline: 1.2096x; 1.0011x over previous
//
#include <hip/hip_runtime.h>
#include <math.h>

#define N_NODES 100000
#define N_EDGES 1600000
#define N_GRAPHS 128
#define IN_DIM 329
#define NH 4
#define CC 64
#define HC 256
#define NEG_SLOPE 0.2f
#define LOG2E 1.44269504f

#define K_PAD 384            // 6 * 64
#define M_PAD 100096         // 1564 * 64
#define XBYTES (N_NODES * IN_DIM * 4)   // 131,600,000
#define NBUCK 196            // buckets of 512 nodes
#define BCAP 10240           // bucket capacity (expected 8673, +16 sigma)
#define EPB 8192             // edges per bin2 block
#define BIN_BLOCKS 208       // ceil((N_EDGES+N_NODES)/EPB)
#define GEMM_BLOCKS (M_PAD / 64)

typedef unsigned short u16;
typedef unsigned char u8;
typedef unsigned int u32;
typedef __attribute__((ext_vector_type(8))) short short8;   // 8 bf16 (4 VGPRs)
typedef __attribute__((ext_vector_type(4))) float floatx4;
typedef __attribute__((ext_vector_type(2))) float floatx2;

__device__ __forceinline__ u16 f2bf(float f) {
    u32 u = __float_as_uint(f);
    u32 r = (u + 0x7FFFu + ((u >> 16) & 1u)) >> 16;   // RNE
    return (u16)r;
}

// pack two f32 -> two bf16 (truncation) in one v_perm_b32
__device__ __forceinline__ u32 pkbf(float a, float b) {
    return __builtin_amdgcn_perm(__float_as_uint(b), __float_as_uint(a), 0x07060302u);
}

// ---- fp8 e4m3 (OCP) helpers: HW path via cvt builtins, SW fallback --------
__device__ __forceinline__ u8 f2fp8(float f) {
#if __has_builtin(__builtin_amdgcn_cvt_pk_fp8_f32)
    int pk = __builtin_amdgcn_cvt_pk_fp8_f32(f, f, 0, false);
    return (u8)(pk & 0xFF);
#else
    u32 u = __float_as_uint(f);
    u32 sgn = (u >> 24) & 0x80;
    float af = fabsf(f);
    if (af >= 448.f) return (u8)(sgn | 0x7E);
    if (af < 0.015625f) {
        int m = (int)rintf(af * 512.f);
        if (m >= 8) return (u8)(sgn | 0x08);
        return (u8)(sgn | (u32)m);
    }
    u32 au = u & 0x7FFFFFFF;
    u32 r = au + 0x0007FFFFu + ((au >> 20) & 1u);
    u32 e = r >> 23;
    u32 m3 = (r >> 20) & 7;
    int fe = (int)e - 127 + 7;
    if (fe >= 16) return (u8)(sgn | 0x7E);
    return (u8)(sgn | ((u32)fe << 3) | m3);
#endif
}

__device__ __forceinline__ float fp82f_sw(u32 b) {
    u32 s = (b & 0x80u) << 24;
    u32 e = (b >> 3) & 0xF;
    u32 m = b & 7;
    if (e == 0) {
        float v = (float)m * 0.001953125f;
        return (b & 0x80) ? -v : v;
    }
    return __uint_as_float(s | ((e + 120) << 23) | (m << 20));
}

__device__ __forceinline__ floatx4 dec4(int p) {
#if __has_builtin(__builtin_amdgcn_cvt_pk_f32_fp8)
    floatx2 lo = __builtin_amdgcn_cvt_pk_f32_fp8(p, false);
    floatx2 hi = __builtin_amdgcn_cvt_pk_f32_fp8(p, true);
    floatx4 r; r.x = lo.x; r.y = lo.y; r.z = hi.x; r.w = hi.y;
    return r;
#else
    floatx4 r;
    r.x = fp82f_sw(p & 0xFF);  r.y = fp82f_sw((p >> 8) & 0xFF);
    r.z = fp82f_sw((p >> 16) & 0xFF); r.w = fp82f_sw((p >> 24) & 0xFF);
    return r;
#endif
}

__device__ __forceinline__ void async_copy16(const void* g, void* l) {
    __builtin_amdgcn_global_load_lds((const __attribute__((address_space(1))) void*)g,
                                     (__attribute__((address_space(3))) void*)l, 16, 0, 0);
}

// ---------------------------------------------------------------------------
// Tiny convert: W (fp32 [329][256]) -> WbT (bf16 [256][K_PAD], transposed)
// ---------------------------------------------------------------------------
__global__ __launch_bounds__(256) void convw_kernel(const float* __restrict__ W, u16* __restrict__ WbT)
{
    int i = blockIdx.x * 256 + threadIdx.x;
    if (i >= HC * 96) return;
    int c = i / 96;
    int k0 = (i - c * 96) * 4;
    ushort4 o = {0, 0, 0, 0};
    const float* wp = W + c;
    if (k0 < IN_DIM)     o.x = f2bf(wp[(size_t)k0 * HC]);
    if (k0 + 1 < IN_DIM) o.y = f2bf(wp[(size_t)(k0 + 1) * HC]);
    if (k0 + 2 < IN_DIM) o.z = f2bf(wp[(size_t)(k0 + 2) * HC]);
    if (k0 + 3 < IN_DIM) o.w = f2bf(wp[(size_t)(k0 + 3) * HC]);
    *(ushort4*)(WbT + (size_t)c * K_PAD + k0) = o;
}

// ---------------------------------------------------------------------------
// Fat kernel: blocks [0, BIN_BLOCKS) run the bin2 edge-bucketing body;
// blocks [BIN_BLOCKS, BIN_BLOCKS+GEMM_BLOCKS) run the v6 MFMA GEMM with
// fused a_src/a_dst epilogue. The two workloads are independent (ei vs x/W),
// previously serialized on the stream; merged, bin2 rides in the GEMM's
// scheduling shadow. LDS: 48K (gemm) + 2.4K (bin) = 50.6K -> 3 blocks/CU.
// ---------------------------------------------------------------------------
__global__ __launch_bounds__(512, 6) void gemm_bin_kernel(
    const float* __restrict__ x, const u16* __restrict__ WbT, u8* __restrict__ xp8,
    const float* __restrict__ att_src, const float* __restrict__ att_dst,
    float* __restrict__ a_src, float* __restrict__ a_dst,
    const int* __restrict__ ei, int* __restrict__ bcur, int2* __restrict__ bins)
{
    __shared__ __align__(16) float Asf[64 * 64];   // 16 KB fp32, 16-chunk XOR swizzled rows
    __shared__ __align__(16) u16   Bs[256 * 64];   // 32 KB bf16, 128B rows, 8-chunk XOR
    __shared__ int hist[NBUCK];
    __shared__ int gpos[NBUCK];
    __shared__ int lcur[NBUCK];

    const int tid = threadIdx.x;

    if (blockIdx.x < BIN_BLOCKS) {
        // ---------------- bin2 body (512 threads) ----------------
        const int lo = blockIdx.x * EPB;
        const int hi = min(lo + EPB, N_EDGES + N_NODES);

        for (int b = tid; b < NBUCK; b += 512) hist[b] = 0;
        __syncthreads();

        for (int i = lo + tid; i < hi; i += 512) {
            int d = (i < N_EDGES) ? ei[N_EDGES + i] : (i - N_EDGES);
            atomicAdd(&hist[d >> 9], 1);
        }
        __syncthreads();

        if (tid < NBUCK) {
            int v = hist[tid];
            gpos[tid] = atomicAdd(&bcur[tid], v);
            lcur[tid] = 0;
        }
        __syncthreads();

        for (int i = lo + tid; i < hi; i += 512) {
            int s, d;
            if (i < N_EDGES) { s = ei[i]; d = ei[N_EDGES + i]; }
            else             { s = i - N_EDGES; d = s; }
            int b = d >> 9;
            int pos = gpos[b] + atomicAdd(&lcur[b], 1);
            if (pos < BCAP) {
                int2 r; r.x = s; r.y = d;
                bins[(size_t)b * BCAP + pos] = r;
            }
        }
        return;
    }

    // ---------------- GEMM body (v6 structure + fused a epilogue) ----------
    const int lane = tid & 63;
    const int wave = tid >> 6;            // 0..7
    const int lr = lane & 15;
    const int q = lane >> 4;
    const int row0 = (blockIdx.x - BIN_BLOCKS) * 64;
    const int rm0 = (wave & 1) * 32;      // row offset within tile (0/32)
    const int cn0 = (wave >> 1) * 64;     // col offset within tile (0/64/128/192)

    floatx4 acc[2][4];
#pragma unroll
    for (int i = 0; i < 2; i++)
#pragma unroll
        for (int j = 0; j < 4; j++) {
            acc[i][j].x = 0.f; acc[i][j].y = 0.f; acc[i][j].z = 0.f; acc[i][j].w = 0.f;
        }

    for (int k0 = 0; k0 < K_PAD; k0 += 64) {
        // stage A: 64 rows x 64 fp32 = 16 KB = 1024 chunks of 16B, 2/thread.
        // physical chunk p at row r holds logical chunk (p ^ (r&15)).
#pragma unroll
        for (int t = 0; t < 2; t++) {
            int chunk = tid + t * 512;
            int row = chunk >> 4, ch = chunk & 15;
            int chl = ch ^ (row & 15);
            long gb = (long)(row0 + row) * (IN_DIM * 4) + (long)k0 * 4 + chl * 16;
            if (gb > (long)XBYTES - 16) gb = (long)XBYTES - 16;   // OOB rows never stored
            async_copy16((const char*)x + gb, (char*)Asf + (size_t)chunk * 16);
        }
        // stage B: 256 cols x 64 k bf16 = 32 KB = 2048 chunks, 4/thread
#pragma unroll
        for (int t = 0; t < 4; t++) {
            int off = (tid + t * 512) * 16;
            int rowb = off >> 7;          // col index 0..255
            int colb = off & 127;         // byte within 128B row
            int gcol = colb ^ ((rowb & 7) * 16);
            const char* gb = (const char*)WbT + (size_t)rowb * (K_PAD * 2) + k0 * 2 + gcol;
            async_copy16(gb, (char*)Bs + off);
        }
        asm volatile("s_waitcnt vmcnt(0)" ::: "memory");
        __syncthreads();

        // compute (R0-proven fragment paths, wave-tile 32x64)
#pragma unroll
        for (int ks = 0; ks < 2; ks++) {
            short8 af[2], bf[4];
#pragma unroll
            for (int i = 0; i < 2; i++) {
                int ra = rm0 + i * 16 + lr;
                int c0 = ks * 8 + q * 2;
                int sw = ra & 15;
                const float4* base = (const float4*)(Asf + ra * 64);
                float4 lo = base[c0 ^ sw];
                float4 hi = base[(c0 ^ sw) ^ 1];          // (c0+1)^sw == (c0^sw)^1 (c0 even)
                union { short8 v; u32 w[4]; } fr;
                fr.w[0] = pkbf(lo.x, lo.y);
                fr.w[1] = pkbf(lo.z, lo.w);
                fr.w[2] = pkbf(hi.x, hi.y);
                fr.w[3] = pkbf(hi.z, hi.w);
                af[i] = fr.v;
            }
#pragma unroll
            for (int j = 0; j < 4; j++) {
                int rb = cn0 + j * 16 + lr;
                int cb = (ks * 64 + q * 16) ^ ((rb & 7) * 16);
                bf[j] = *(const short8*)((const char*)Bs + rb * 128 + cb);
            }
#pragma unroll
            for (int i = 0; i < 2; i++)
#pragma unroll
                for (int j = 0; j < 4; j++)
                    acc[i][j] = __builtin_amdgcn_mfma_f32_16x16x32_bf16(af[i], bf[j], acc[i][j], 0, 0, 0);
        }
        __syncthreads();
    }

    // epilogue 1: fp8 store (C/D layout: col=lane&15 block, row=q*4+reg)
#pragma unroll
    for (int i = 0; i < 2; i++) {
#pragma unroll
        for (int j = 0; j < 4; j++) {
            int col = cn0 + j * 16 + lr;
            float v[4] = {acc[i][j].x, acc[i][j].y, acc[i][j].z, acc[i][j].w};
#pragma unroll
            for (int r = 0; r < 4; r++) {
                int row = row0 + rm0 + i * 16 + q * 4 + r;
                if (row < N_NODES) xp8[(size_t)row * HC + col] = f2fp8(v[r]);
            }
        }
    }

    // epilogue 2: fused a_src/a_dst. This wave's 64 cols = head (wave>>1).
    float as0 = att_src[cn0 + 0 * 16 + lr], ad0 = att_dst[cn0 + 0 * 16 + lr];
    float as1 = att_src[cn0 + 1 * 16 + lr], ad1 = att_dst[cn0 + 1 * 16 + lr];
    float as2 = att_src[cn0 + 2 * 16 + lr], ad2 = att_dst[cn0 + 2 * 16 + lr];
    float as3 = att_src[cn0 + 3 * 16 + lr], ad3 = att_dst[cn0 + 3 * 16 + lr];

    float ps[2][4], pd[2][4];
#pragma unroll
    for (int i = 0; i < 2; i++) {
        ps[i][0] = acc[i][0].x * as0 + acc[i][1].x * as1 + acc[i][2].x * as2 + acc[i][3].x * as3;
        ps[i][1] = acc[i][0].y * as0 + acc[i][1].y * as1 + acc[i][2].y * as2 + acc[i][3].y * as3;
        ps[i][2] = acc[i][0].z * as0 + acc[i][1].z * as1 + acc[i][2].z * as2 + acc[i][3].z * as3;
        ps[i][3] = acc[i][0].w * as0 + acc[i][1].w * as1 + acc[i][2].w * as2 + acc[i][3].w * as3;
        pd[i][0] = acc[i][0].x * ad0 + acc[i][1].x * ad1 + acc[i][2].x * ad2 + acc[i][3].x * ad3;
        pd[i][1] = acc[i][0].y * ad0 + acc[i][1].y * ad1 + acc[i][2].y * ad2 + acc[i][3].y * ad3;
        pd[i][2] = acc[i][0].z * ad0 + acc[i][1].z * ad1 + acc[i][2].z * ad2 + acc[i][3].z * ad3;
        pd[i][3] = acc[i][0].w * ad0 + acc[i][1].w * ad1 + acc[i][2].w * ad2 + acc[i][3].w * ad3;
    }
#pragma unroll
    for (int m = 1; m < 16; m <<= 1) {
#pragma unroll
        for (int i = 0; i < 2; i++) {
#pragma unroll
            for (int r = 0; r < 4; r++) {
                ps[i][r] += __shfl_xor(ps[i][r], m, 64);
                pd[i][r] += __shfl_xor(pd[i][r], m, 64);
            }
        }
    }
    if (lr == 0) {
        int head = wave >> 1;
#pragma unroll
        for (int i = 0; i < 2; i++) {
#pragma unroll
            for (int r = 0; r < 4; r++) {
                int row = row0 + rm0 + i * 16 + q * 4 + r;
                if (row < N_NODES) {
                    a_src[row * 4 + head] = ps[i][r] * LOG2E;
                    a_dst[row * 4 + head] = pd[i][r] * LOG2E;
                }
            }
        }
    }
}

// ---------------------------------------------------------------------------
// Pass 2: one 512-thread block per bucket. LDS counting sort -> compact CSR.
// ---------------------------------------------------------------------------
__global__ __launch_bounds__(512) void fill3_kernel(
    const int* __restrict__ bcur, const int2* __restrict__ bins,
    int2* __restrict__ rs_deg, int* __restrict__ csr)
{
    __shared__ int deg[512];
    __shared__ int cur[512];
    __shared__ int sc[256];
    __shared__ int order[BCAP];

    const int t = threadIdx.x;
    const int b = blockIdx.x;
    const int cnt = min(bcur[b], BCAP);
    const int2* bp = bins + (size_t)b * BCAP;
    const int gbase = b * BCAP;

    deg[t] = 0;
    __syncthreads();
    for (int i = t; i < cnt; i += 512) atomicAdd(&deg[bp[i].y & 511], 1);
    __syncthreads();

    int d0 = 0, d1 = 0;
    if (t < 256) {
        d0 = deg[2 * t]; d1 = deg[2 * t + 1];
        sc[t] = d0 + d1;
    }
    __syncthreads();
    for (int off = 1; off < 256; off <<= 1) {
        int u = (t < 256 && t >= off) ? sc[t - off] : 0;
        __syncthreads();
        if (t < 256) sc[t] += u;
        __syncthreads();
    }
    if (t < 256) {
        int excl = sc[t] - (d0 + d1);
        cur[2 * t] = excl;
        cur[2 * t + 1] = excl + d0;
        int n0 = b * 512 + 2 * t;
        if (n0 < N_NODES)     { int2 rd; rd.x = gbase + excl;      rd.y = d0; rs_deg[n0] = rd; }
        if (n0 + 1 < N_NODES) { int2 rd; rd.x = gbase + excl + d0; rd.y = d1; rs_deg[n0 + 1] = rd; }
    }
    __syncthreads();

    for (int i = t; i < cnt; i += 512) {
        int2 r = bp[i];
        int pos = atomicAdd(&cur[r.y & 511], 1);
        order[pos] = r.x;
    }
    __syncthreads();

    for (int i = t; i < cnt; i += 512) csr[gbase + i] = order[i];
}

// ---------------------------------------------------------------------------
// Fused single-pass segment softmax + fp8 aggregation + head-mean + bias/relu.
// Software-pipelined gather loop (R1-proven form, no block barrier).
// ---------------------------------------------------------------------------
__global__ __launch_bounds__(256) void aggregate_kernel(
    const u8* __restrict__ xp8, const float* __restrict__ a_src, const float* __restrict__ a_dst,
    const int2* __restrict__ rs_deg, const int* __restrict__ csr,
    const float* __restrict__ bias, float* __restrict__ hbuf)
{
    int n = blockIdx.x * 4 + (threadIdx.x >> 6);
    int lane = threadIdx.x & 63;
    if (n >= N_NODES) return;
    int2 rd = rs_deg[n];
    int rstart = __builtin_amdgcn_readfirstlane(rd.x);
    int deg    = __builtin_amdgcn_readfirstlane(rd.y);
    const int* ep = csr + rstart;
    int h = lane >> 4;
    int xoff = lane * 4;

    float ad = a_dst[n * 4 + h];

    const int dm1 = deg - 1;          // deg >= 1 (self-loop)
    const int nb  = (deg + 3) >> 2;

    float acc0 = 0.f, acc1 = 0.f, acc2 = 0.f, acc3 = 0.f, den = 0.f;

    // pipeline state
    int iA0, iA1, iA2, iA3;                       // idx, even-slot batches (SGPR)
    int iB0 = 0, iB1 = 0, iB2 = 0, iB3 = 0;       // idx, odd-slot batches (SGPR)
    float aa0, aa1, aa2, aa3;  int pa0, pa1, pa2, pa3;   // data buffer A
    float ab0, ab1, ab2, ab3;  int pb0, pb1, pb2, pb3;   // data buffer B

#define AGG_LDI(eb_, j0, j1, j2, j3) do { \
        j0 = ep[min((eb_), dm1)];     j1 = ep[min((eb_) + 1, dm1)]; \
        j2 = ep[min((eb_) + 2, dm1)]; j3 = ep[min((eb_) + 3, dm1)]; } while (0)

#define AGG_LDD(j0, j1, j2, j3, a0_, a1_, a2_, a3_, q0_, q1_, q2_, q3_) do { \
        a0_ = a_src[(size_t)(j0) * 4 + h];  q0_ = *(const int*)(xp8 + (size_t)(j0) * HC + xoff); \
        a1_ = a_src[(size_t)(j1) * 4 + h];  q1_ = *(const int*)(xp8 + (size_t)(j1) * HC + xoff); \
        a2_ = a_src[(size_t)(j2) * 4 + h];  q2_ = *(const int*)(xp8 + (size_t)(j2) * HC + xoff); \
        a3_ = a_src[(size_t)(j3) * 4 + h];  q3_ = *(const int*)(xp8 + (size_t)(j3) * HC + xoff); } while (0)

#define AGG_CMP(eb_, a0_, a1_, a2_, a3_, q0_, q1_, q2_, q3_) do { \
        float z0 = a0_ + ad, z1 = a1_ + ad, z2 = a2_ + ad, z3 = a3_ + ad; \
        float w0 = exp2f(fmaxf(z0, NEG_SLOPE * z0)); \
        float w1 = exp2f(fmaxf(z1, NEG_SLOPE * z1)); \
        float w2 = exp2f(fmaxf(z2, NEG_SLOPE * z2)); \
        float w3 = exp2f(fmaxf(z3, NEG_SLOPE * z3)); \
        if ((eb_) + 3 >= deg) {               /* wave-uniform, taken only on last batch */ \
            if ((eb_) + 1 >= deg) w1 = 0.f; \
            if ((eb_) + 2 >= deg) w2 = 0.f; \
            if ((eb_) + 3 >= deg) w3 = 0.f; \
        } \
        den += (w0 + w1) + (w2 + w3); \
        floatx4 v0 = dec4(q0_), v1 = dec4(q1_), v2 = dec4(q2_), v3 = dec4(q3_); \
        acc0 = fmaf(w0, v0.x, acc0); acc1 = fmaf(w0, v0.y, acc1); \
        acc2 = fmaf(w0, v0.z, acc2); acc3 = fmaf(w0, v0.w, acc3); \
        acc0 = fmaf(w1, v1.x, acc0); acc1 = fmaf(w1, v1.y, acc1); \
        acc2 = fmaf(w1, v1.z, acc2); acc3 = fmaf(w1, v1.w, acc3); \
        acc0 = fmaf(w2, v2.x, acc0); acc1 = fmaf(w2, v2.y, acc1); \
        acc2 = fmaf(w2, v2.z, acc2); acc3 = fmaf(w2, v2.w, acc3); \
        acc0 = fmaf(w3, v3.x, acc0); acc1 = fmaf(w3, v3.y, acc1); \
        acc2 = fmaf(w3, v3.z, acc2); acc3 = fmaf(w3, v3.w, acc3); } while (0)

    // prologue: batch 0 idx + data, batch 1 idx
    AGG_LDI(0, iA0, iA1, iA2, iA3);
    AGG_LDD(iA0, iA1, iA2, iA3, aa0, aa1, aa2, aa3, pa0, pa1, pa2, pa3);
    if (nb > 1) AGG_LDI(4, iB0, iB1, iB2, iB3);

    for (int b = 0; b < nb; b += 2) {
        int eb = b * 4;
        // even slot: data(b+1)->bufB first (its idx is old), then idx(b+2)->iA
        if (b + 1 < nb) AGG_LDD(iB0, iB1, iB2, iB3, ab0, ab1, ab2, ab3, pb0, pb1, pb2, pb3);
        if (b + 2 < nb) AGG_LDI(eb + 8, iA0, iA1, iA2, iA3);
        AGG_CMP(eb, aa0, aa1, aa2, aa3, pa0, pa1, pa2, pa3);
        if (b + 1 < nb) {
            // odd slot
            if (b + 2 < nb) AGG_LDD(iA0, iA1, iA2, iA3, aa0, aa1, aa2, aa3, pa0, pa1, pa2, pa3);
            if (b + 3 < nb) AGG_LDI(eb + 12, iB0, iB1, iB2, iB3);
            AGG_CMP(eb + 4, ab0, ab1, ab2, ab3, pb0, pb1, pb2, pb3);
        }
    }

#undef AGG_LDI
#undef AGG_LDD
#undef AGG_CMP

    float r = 1.f / den;
    acc0 *= r; acc1 *= r; acc2 *= r; acc3 *= r;
#pragma unroll
    for (int m = 16; m <= 32; m <<= 1) {
        acc0 += __shfl_xor(acc0, m, 64);
        acc1 += __shfl_xor(acc1, m, 64);
        acc2 += __shfl_xor(acc2, m, 64);
        acc3 += __shfl_xor(acc3, m, 64);
    }
    if (lane < 16) {
        const float* bp = bias + lane * 4;
        float4 o;
        o.x = fmaxf(0.25f * acc0 + bp[0], 0.f);
        o.y = fmaxf(0.25f * acc1 + bp[1], 0.f);
        o.z = fmaxf(0.25f * acc2 + bp[2], 0.f);
        o.w = fmaxf(0.25f * acc3 + bp[3], 0.f);
        *(float4*)&hbuf[(size_t)n * CC + lane * 4] = o;
    }
}

// ---------------------------------------------------------------------------
// Fused mean-pool + MLP head: one block per graph. batch is sorted, so each
// graph's node range comes from two binary searches; 4 waves stride the rows
// (coalesced 256B row reads, 4-deep independent), LDS-reduce, wave 0 runs
// the MLP. Replaces pool1 (atomics over 25.6 MB) + pool2 + gsum/gcnt bufs.
// ---------------------------------------------------------------------------
__global__ __launch_bounds__(256) void pool_kernel(
    const float* __restrict__ hbuf, const int* __restrict__ batch,
    const float* __restrict__ w1, const float* __restrict__ b1,
    const float* __restrict__ w2, const float* __restrict__ b2,
    float* __restrict__ out)
{
    __shared__ float part[4][64];
    __shared__ float gv[64];

    const int g = blockIdx.x;
    const int lane = threadIdx.x & 63;
    const int w = threadIdx.x >> 6;

    // lower_bound(batch, g) / lower_bound(batch, g+1)
    int lo = 0, hi = N_NODES;
    while (lo < hi) { int m = (lo + hi) >> 1; if (batch[m] < g) lo = m + 1; else hi = m; }
    const int start = lo;
    hi = N_NODES;
    while (lo < hi) { int m = (lo + hi) >> 1; if (batch[m] < g + 1) lo = m + 1; else hi = m; }
    const int end = lo;
    const int cnt = end - start;

    // 4-deep unrolled row accumulation (independent loads in flight)
    float s0 = 0.f, s1 = 0.f, s2 = 0.f, s3 = 0.f;
    int r = start + w;
    for (; r + 12 < end; r += 16) {
        s0 += hbuf[(size_t)r * CC + lane];
        s1 += hbuf[(size_t)(r + 4) * CC + lane];
        s2 += hbuf[(size_t)(r + 8) * CC + lane];
        s3 += hbuf[(size_t)(r + 12) * CC + lane];
    }
    for (; r < end; r += 4) s0 += hbuf[(size_t)r * CC + lane];
    part[w][lane] = (s0 + s1) + (s2 + s3);
    __syncthreads();

    if (threadIdx.x < 64) {
        float t = (part[0][lane] + part[1][lane]) + (part[2][lane] + part[3][lane]);
        gv[lane] = t / (float)max(cnt, 1);
    }
    __syncthreads();

    if (w == 0) {
        float hid = b1[lane];
        for (int c = 0; c < 64; c++) hid = fmaf(gv[c], w1[c * 64 + lane], hid);
        hid = fmaxf(hid, 0.f);
        float p = hid * w2[lane];
#pragma unroll
        for (int off = 32; off > 0; off >>= 1) p += __shfl_xor(p, off, 64);
        if (lane == 0) out[g] = 1.f / (1.f + __expf(-(p + b2[0])));
    }
}

// ---------------------------------------------------------------------------
extern "C" void kernel_launch(void* const* d_in, const int* in_sizes, int n_in,
                              void* d_out, int out_size, void* d_ws, size_t ws_size,
                              hipStream_t stream)
{
    const float* x       = (const float*)d_in[0];
    const float* W       = (const float*)d_in[1];
    const float* att_src = (const float*)d_in[2];
    const float* att_dst = (const float*)d_in[3];
    const float* bias    = (const float*)d_in[4];
    const float* w1      = (const float*)d_in[5];
    const float* b1      = (const float*)d_in[6];
    const float* w2      = (const float*)d_in[7];
    const float* b2      = (const float*)d_in[8];
    const int*   ei      = (const int*)d_in[9];
    const int*   batch   = (const int*)d_in[10];
    float* out = (float*)d_out;

    char* ws = (char*)d_ws;
    size_t off = 0;
    auto alloc = [&](size_t bytes) -> void* {
        void* p = ws + off;
        off += (bytes + 255) & ~(size_t)255;
        return p;
    };
    u16*   WbT       = (u16*)alloc((size_t)HC * K_PAD * 2);             // 196 KB
    u8*    xp8       = (u8*)alloc((size_t)N_NODES * HC);                // 25.6 MB
    float* a_src_b   = (float*)alloc((size_t)N_NODES * NH * 4);
    float* a_dst_b   = (float*)alloc((size_t)N_NODES * NH * 4);
    size_t zoff0 = off;
    int*   bcur      = (int*)alloc((size_t)NBUCK * 4);                  // zeroed
    size_t zbytes = off - zoff0;
    int2*  bins      = (int2*)alloc((size_t)NBUCK * BCAP * 8);          // 16.1 MB
    int2*  rs_deg    = (int2*)alloc((size_t)N_NODES * 8);               // 800 KB
    int*   csr       = (int*)alloc((size_t)NBUCK * BCAP * 4);           // 8 MB
    float* hbuf      = (float*)alloc((size_t)N_NODES * CC * 4);         // 25.6 MB

    hipMemsetAsync(bcur, 0, zbytes, stream);

    convw_kernel<<<(HC * 96 + 255) / 256, 256, 0, stream>>>(W, WbT);

    gemm_bin_kernel<<<BIN_BLOCKS + GEMM_BLOCKS, 512, 0, stream>>>(
        x, WbT, xp8, att_src, att_dst, a_src_b, a_dst_b, ei, bcur, bins);

    fill3_kernel<<<NBUCK, 512, 0, stream>>>(bcur, bins, rs_deg, csr);

    aggregate_kernel<<<(N_NODES + 3) / 4, 256, 0, stream>>>(xp8, a_src_b, a_dst_b,
                                                            rs_deg, csr, bias, hbuf);

    pool_kernel<<<N_GRAPHS, 256, 0, stream>>>(hbuf, batch, w1, b1, w2, b2, out);
}

// Round 11
// 382.508 us; speedup vs baseline: 1.2131x; 1.0029x over previous
//
#include <hip/hip_runtime.h>
#include <math.h>

#define N_NODES 100000
#define N_EDGES 1600000
#define N_GRAPHS 128
#define IN_DIM 329
#define NH 4
#define CC 64
#define HC 256
#define NEG_SLOPE 0.2f
#define LOG2E 1.44269504f

#define K_PAD 384            // 6 * 64
#define M_PAD 100096         // 1564 * 64
#define XBYTES (N_NODES * IN_DIM * 4)   // 131,600,000
#define NBUCK 196            // buckets of 512 nodes
#define BCAP 10240           // bucket capacity (expected 8673, +16 sigma)
#define EPB 8192             // edges per bin2 block
#define BIN_BLOCKS 208       // ceil((N_EDGES+N_NODES)/EPB)
#define GEMM_BLOCKS (M_PAD / 64)

typedef unsigned short u16;
typedef unsigned char u8;
typedef unsigned int u32;
typedef __attribute__((ext_vector_type(8))) short short8;   // 8 bf16 (4 VGPRs)
typedef __attribute__((ext_vector_type(4))) float floatx4;
typedef __attribute__((ext_vector_type(2))) float floatx2;

__device__ __forceinline__ u16 f2bf(float f) {
    u32 u = __float_as_uint(f);
    u32 r = (u + 0x7FFFu + ((u >> 16) & 1u)) >> 16;   // RNE
    return (u16)r;
}

// pack two f32 -> two bf16 (truncation) in one v_perm_b32
__device__ __forceinline__ u32 pkbf(float a, float b) {
    return __builtin_amdgcn_perm(__float_as_uint(b), __float_as_uint(a), 0x07060302u);
}

// ---- fp8 e4m3 (OCP) helpers: HW path via cvt builtins, SW fallback --------
__device__ __forceinline__ u8 f2fp8(float f) {
#if __has_builtin(__builtin_amdgcn_cvt_pk_fp8_f32)
    int pk = __builtin_amdgcn_cvt_pk_fp8_f32(f, f, 0, false);
    return (u8)(pk & 0xFF);
#else
    u32 u = __float_as_uint(f);
    u32 sgn = (u >> 24) & 0x80;
    float af = fabsf(f);
    if (af >= 448.f) return (u8)(sgn | 0x7E);
    if (af < 0.015625f) {
        int m = (int)rintf(af * 512.f);
        if (m >= 8) return (u8)(sgn | 0x08);
        return (u8)(sgn | (u32)m);
    }
    u32 au = u & 0x7FFFFFFF;
    u32 r = au + 0x0007FFFFu + ((au >> 20) & 1u);
    u32 e = r >> 23;
    u32 m3 = (r >> 20) & 7;
    int fe = (int)e - 127 + 7;
    if (fe >= 16) return (u8)(sgn | 0x7E);
    return (u8)(sgn | ((u32)fe << 3) | m3);
#endif
}

__device__ __forceinline__ float fp82f_sw(u32 b) {
    u32 s = (b & 0x80u) << 24;
    u32 e = (b >> 3) & 0xF;
    u32 m = b & 7;
    if (e == 0) {
        float v = (float)m * 0.001953125f;
        return (b & 0x80) ? -v : v;
    }
    return __uint_as_float(s | ((e + 120) << 23) | (m << 20));
}

__device__ __forceinline__ floatx4 dec4(int p) {
#if __has_builtin(__builtin_amdgcn_cvt_pk_f32_fp8)
    floatx2 lo = __builtin_amdgcn_cvt_pk_f32_fp8(p, false);
    floatx2 hi = __builtin_amdgcn_cvt_pk_f32_fp8(p, true);
    floatx4 r; r.x = lo.x; r.y = lo.y; r.z = hi.x; r.w = hi.y;
    return r;
#else
    floatx4 r;
    r.x = fp82f_sw(p & 0xFF);  r.y = fp82f_sw((p >> 8) & 0xFF);
    r.z = fp82f_sw((p >> 16) & 0xFF); r.w = fp82f_sw((p >> 24) & 0xFF);
    return r;
#endif
}

__device__ __forceinline__ void async_copy16(const void* g, void* l) {
    __builtin_amdgcn_global_load_lds((const __attribute__((address_space(1))) void*)g,
                                     (__attribute__((address_space(3))) void*)l, 16, 0, 0);
}

// ---------------------------------------------------------------------------
// Tiny convert: W (fp32 [329][256]) -> WbT (bf16 [256][K_PAD], transposed)
// ---------------------------------------------------------------------------
__global__ __launch_bounds__(256) void convw_kernel(const float* __restrict__ W, u16* __restrict__ WbT)
{
    int i = blockIdx.x * 256 + threadIdx.x;
    if (i >= HC * 96) return;
    int c = i / 96;
    int k0 = (i - c * 96) * 4;
    ushort4 o = {0, 0, 0, 0};
    const float* wp = W + c;
    if (k0 < IN_DIM)     o.x = f2bf(wp[(size_t)k0 * HC]);
    if (k0 + 1 < IN_DIM) o.y = f2bf(wp[(size_t)(k0 + 1) * HC]);
    if (k0 + 2 < IN_DIM) o.z = f2bf(wp[(size_t)(k0 + 2) * HC]);
    if (k0 + 3 < IN_DIM) o.w = f2bf(wp[(size_t)(k0 + 3) * HC]);
    *(ushort4*)(WbT + (size_t)c * K_PAD + k0) = o;
}

// ---------------------------------------------------------------------------
// Fat kernel: blocks [0, BIN_BLOCKS) run the bin2 edge-bucketing body;
// blocks [BIN_BLOCKS, BIN_BLOCKS+GEMM_BLOCKS) run the v6 MFMA GEMM with
// fused a_src/a_dst epilogue. The two workloads are independent (ei vs x/W),
// previously serialized on the stream; merged, bin2 rides in the GEMM's
// scheduling shadow. LDS: 48K (gemm) + 2.4K (bin) = 50.6K -> 3 blocks/CU.
// ---------------------------------------------------------------------------
__global__ __launch_bounds__(512, 6) void gemm_bin_kernel(
    const float* __restrict__ x, const u16* __restrict__ WbT, u8* __restrict__ xp8,
    const float* __restrict__ att_src, const float* __restrict__ att_dst,
    float* __restrict__ a_src, float* __restrict__ a_dst,
    const int* __restrict__ ei, int* __restrict__ bcur, int2* __restrict__ bins)
{
    __shared__ __align__(16) float Asf[64 * 64];   // 16 KB fp32, 16-chunk XOR swizzled rows
    __shared__ __align__(16) u16   Bs[256 * 64];   // 32 KB bf16, 128B rows, 8-chunk XOR
    __shared__ int hist[NBUCK];
    __shared__ int gpos[NBUCK];
    __shared__ int lcur[NBUCK];

    const int tid = threadIdx.x;

    if (blockIdx.x < BIN_BLOCKS) {
        // ---------------- bin2 body (512 threads) ----------------
        const int lo = blockIdx.x * EPB;
        const int hi = min(lo + EPB, N_EDGES + N_NODES);

        for (int b = tid; b < NBUCK; b += 512) hist[b] = 0;
        __syncthreads();

        for (int i = lo + tid; i < hi; i += 512) {
            int d = (i < N_EDGES) ? ei[N_EDGES + i] : (i - N_EDGES);
            atomicAdd(&hist[d >> 9], 1);
        }
        __syncthreads();

        if (tid < NBUCK) {
            int v = hist[tid];
            gpos[tid] = atomicAdd(&bcur[tid], v);
            lcur[tid] = 0;
        }
        __syncthreads();

        for (int i = lo + tid; i < hi; i += 512) {
            int s, d;
            if (i < N_EDGES) { s = ei[i]; d = ei[N_EDGES + i]; }
            else             { s = i - N_EDGES; d = s; }
            int b = d >> 9;
            int pos = gpos[b] + atomicAdd(&lcur[b], 1);
            if (pos < BCAP) {
                int2 r; r.x = s; r.y = d;
                bins[(size_t)b * BCAP + pos] = r;
            }
        }
        return;
    }

    // ---------------- GEMM body (v6 structure + fused a epilogue) ----------
    const int lane = tid & 63;
    const int wave = tid >> 6;            // 0..7
    const int lr = lane & 15;
    const int q = lane >> 4;
    const int row0 = (blockIdx.x - BIN_BLOCKS) * 64;
    const int rm0 = (wave & 1) * 32;      // row offset within tile (0/32)
    const int cn0 = (wave >> 1) * 64;     // col offset within tile (0/64/128/192)

    floatx4 acc[2][4];
#pragma unroll
    for (int i = 0; i < 2; i++)
#pragma unroll
        for (int j = 0; j < 4; j++) {
            acc[i][j].x = 0.f; acc[i][j].y = 0.f; acc[i][j].z = 0.f; acc[i][j].w = 0.f;
        }

    for (int k0 = 0; k0 < K_PAD; k0 += 64) {
        // stage A: 64 rows x 64 fp32 = 16 KB = 1024 chunks of 16B, 2/thread.
        // physical chunk p at row r holds logical chunk (p ^ (r&15)).
#pragma unroll
        for (int t = 0; t < 2; t++) {
            int chunk = tid + t * 512;
            int row = chunk >> 4, ch = chunk & 15;
            int chl = ch ^ (row & 15);
            long gb = (long)(row0 + row) * (IN_DIM * 4) + (long)k0 * 4 + chl * 16;
            if (gb > (long)XBYTES - 16) gb = (long)XBYTES - 16;   // OOB rows never stored
            async_copy16((const char*)x + gb, (char*)Asf + (size_t)chunk * 16);
        }
        // stage B: 256 cols x 64 k bf16 = 32 KB = 2048 chunks, 4/thread
#pragma unroll
        for (int t = 0; t < 4; t++) {
            int off = (tid + t * 512) * 16;
            int rowb = off >> 7;          // col index 0..255
            int colb = off & 127;         // byte within 128B row
            int gcol = colb ^ ((rowb & 7) * 16);
            const char* gb = (const char*)WbT + (size_t)rowb * (K_PAD * 2) + k0 * 2 + gcol;
            async_copy16(gb, (char*)Bs + off);
        }
        asm volatile("s_waitcnt vmcnt(0)" ::: "memory");
        __syncthreads();

        // compute (R0-proven fragment paths, wave-tile 32x64)
#pragma unroll
        for (int ks = 0; ks < 2; ks++) {
            short8 af[2], bf[4];
#pragma unroll
            for (int i = 0; i < 2; i++) {
                int ra = rm0 + i * 16 + lr;
                int c0 = ks * 8 + q * 2;
                int sw = ra & 15;
                const float4* base = (const float4*)(Asf + ra * 64);
                float4 lo = base[c0 ^ sw];
                float4 hi = base[(c0 ^ sw) ^ 1];          // (c0+1)^sw == (c0^sw)^1 (c0 even)
                union { short8 v; u32 w[4]; } fr;
                fr.w[0] = pkbf(lo.x, lo.y);
                fr.w[1] = pkbf(lo.z, lo.w);
                fr.w[2] = pkbf(hi.x, hi.y);
                fr.w[3] = pkbf(hi.z, hi.w);
                af[i] = fr.v;
            }
#pragma unroll
            for (int j = 0; j < 4; j++) {
                int rb = cn0 + j * 16 + lr;
                int cb = (ks * 64 + q * 16) ^ ((rb & 7) * 16);
                bf[j] = *(const short8*)((const char*)Bs + rb * 128 + cb);
            }
#pragma unroll
            for (int i = 0; i < 2; i++)
#pragma unroll
                for (int j = 0; j < 4; j++)
                    acc[i][j] = __builtin_amdgcn_mfma_f32_16x16x32_bf16(af[i], bf[j], acc[i][j], 0, 0, 0);
        }
        __syncthreads();
    }

    // epilogue 1: fp8 store (C/D layout: col=lane&15 block, row=q*4+reg)
#pragma unroll
    for (int i = 0; i < 2; i++) {
#pragma unroll
        for (int j = 0; j < 4; j++) {
            int col = cn0 + j * 16 + lr;
            float v[4] = {acc[i][j].x, acc[i][j].y, acc[i][j].z, acc[i][j].w};
#pragma unroll
            for (int r = 0; r < 4; r++) {
                int row = row0 + rm0 + i * 16 + q * 4 + r;
                if (row < N_NODES) xp8[(size_t)row * HC + col] = f2fp8(v[r]);
            }
        }
    }

    // epilogue 2: fused a_src/a_dst. This wave's 64 cols = head (wave>>1).
    float as0 = att_src[cn0 + 0 * 16 + lr], ad0 = att_dst[cn0 + 0 * 16 + lr];
    float as1 = att_src[cn0 + 1 * 16 + lr], ad1 = att_dst[cn0 + 1 * 16 + lr];
    float as2 = att_src[cn0 + 2 * 16 + lr], ad2 = att_dst[cn0 + 2 * 16 + lr];
    float as3 = att_src[cn0 + 3 * 16 + lr], ad3 = att_dst[cn0 + 3 * 16 + lr];

    float ps[2][4], pd[2][4];
#pragma unroll
    for (int i = 0; i < 2; i++) {
        ps[i][0] = acc[i][0].x * as0 + acc[i][1].x * as1 + acc[i][2].x * as2 + acc[i][3].x * as3;
        ps[i][1] = acc[i][0].y * as0 + acc[i][1].y * as1 + acc[i][2].y * as2 + acc[i][3].y * as3;
        ps[i][2] = acc[i][0].z * as0 + acc[i][1].z * as1 + acc[i][2].z * as2 + acc[i][3].z * as3;
        ps[i][3] = acc[i][0].w * as0 + acc[i][1].w * as1 + acc[i][2].w * as2 + acc[i][3].w * as3;
        pd[i][0] = acc[i][0].x * ad0 + acc[i][1].x * ad1 + acc[i][2].x * ad2 + acc[i][3].x * ad3;
        pd[i][1] = acc[i][0].y * ad0 + acc[i][1].y * ad1 + acc[i][2].y * ad2 + acc[i][3].y * ad3;
        pd[i][2] = acc[i][0].z * ad0 + acc[i][1].z * ad1 + acc[i][2].z * ad2 + acc[i][3].z * ad3;
        pd[i][3] = acc[i][0].w * ad0 + acc[i][1].w * ad1 + acc[i][2].w * ad2 + acc[i][3].w * ad3;
    }
#pragma unroll
    for (int m = 1; m < 16; m <<= 1) {
#pragma unroll
        for (int i = 0; i < 2; i++) {
#pragma unroll
            for (int r = 0; r < 4; r++) {
                ps[i][r] += __shfl_xor(ps[i][r], m, 64);
                pd[i][r] += __shfl_xor(pd[i][r], m, 64);
            }
        }
    }
    if (lr == 0) {
        int head = wave >> 1;
#pragma unroll
        for (int i = 0; i < 2; i++) {
#pragma unroll
            for (int r = 0; r < 4; r++) {
                int row = row0 + rm0 + i * 16 + q * 4 + r;
                if (row < N_NODES) {
                    a_src[row * 4 + head] = ps[i][r] * LOG2E;
                    a_dst[row * 4 + head] = pd[i][r] * LOG2E;
                }
            }
        }
    }
}

// ---------------------------------------------------------------------------
// Pass 2: one 512-thread block per bucket. LDS counting sort -> compact CSR.
// ---------------------------------------------------------------------------
__global__ __launch_bounds__(512) void fill3_kernel(
    const int* __restrict__ bcur, const int2* __restrict__ bins,
    int2* __restrict__ rs_deg, int* __restrict__ csr)
{
    __shared__ int deg[512];
    __shared__ int cur[512];
    __shared__ int sc[256];
    __shared__ int order[BCAP];

    const int t = threadIdx.x;
    const int b = blockIdx.x;
    const int cnt = min(bcur[b], BCAP);
    const int2* bp = bins + (size_t)b * BCAP;
    const int gbase = b * BCAP;

    deg[t] = 0;
    __syncthreads();
    for (int i = t; i < cnt; i += 512) atomicAdd(&deg[bp[i].y & 511], 1);
    __syncthreads();

    int d0 = 0, d1 = 0;
    if (t < 256) {
        d0 = deg[2 * t]; d1 = deg[2 * t + 1];
        sc[t] = d0 + d1;
    }
    __syncthreads();
    for (int off = 1; off < 256; off <<= 1) {
        int u = (t < 256 && t >= off) ? sc[t - off] : 0;
        __syncthreads();
        if (t < 256) sc[t] += u;
        __syncthreads();
    }
    if (t < 256) {
        int excl = sc[t] - (d0 + d1);
        cur[2 * t] = excl;
        cur[2 * t + 1] = excl + d0;
        int n0 = b * 512 + 2 * t;
        if (n0 < N_NODES)     { int2 rd; rd.x = gbase + excl;      rd.y = d0; rs_deg[n0] = rd; }
        if (n0 + 1 < N_NODES) { int2 rd; rd.x = gbase + excl + d0; rd.y = d1; rs_deg[n0 + 1] = rd; }
    }
    __syncthreads();

    for (int i = t; i < cnt; i += 512) {
        int2 r = bp[i];
        int pos = atomicAdd(&cur[r.y & 511], 1);
        order[pos] = r.x;
    }
    __syncthreads();

    for (int i = t; i < cnt; i += 512) csr[gbase + i] = order[i];
}

// ---------------------------------------------------------------------------
// Fused single-pass segment softmax + fp8 aggregation + head-mean + bias/relu.
// Software-pipelined gather loop (R1-proven form). This round: packed-FP32
// inner math (v_pk_fma/add/mul via float2 vectors) — VALUBusy was 80%, so
// the f32 ALU stream is the pipe to shrink: fmaf 16->8, z-add 4->2,
// slope-mul 4->2 per 4-edge batch.
// ---------------------------------------------------------------------------
__global__ __launch_bounds__(256) void aggregate_kernel(
    const u8* __restrict__ xp8, const float* __restrict__ a_src, const float* __restrict__ a_dst,
    const int2* __restrict__ rs_deg, const int* __restrict__ csr,
    const float* __restrict__ bias, float* __restrict__ hbuf)
{
    int n = blockIdx.x * 4 + (threadIdx.x >> 6);
    int lane = threadIdx.x & 63;
    if (n >= N_NODES) return;
    int2 rd = rs_deg[n];
    int rstart = __builtin_amdgcn_readfirstlane(rd.x);
    int deg    = __builtin_amdgcn_readfirstlane(rd.y);
    const int* ep = csr + rstart;
    int h = lane >> 4;
    int xoff = lane * 4;

    float ad = a_dst[n * 4 + h];
    const floatx2 adv = {ad, ad};
    const floatx2 nsv = {NEG_SLOPE, NEG_SLOPE};

    const int dm1 = deg - 1;          // deg >= 1 (self-loop)
    const int nb  = (deg + 3) >> 2;

    floatx2 acc01 = {0.f, 0.f}, acc23 = {0.f, 0.f};
    float den = 0.f;

    // pipeline state
    int iA0, iA1, iA2, iA3;                       // idx, even-slot batches (SGPR)
    int iB0 = 0, iB1 = 0, iB2 = 0, iB3 = 0;       // idx, odd-slot batches (SGPR)
    float aa0, aa1, aa2, aa3;  int pa0, pa1, pa2, pa3;   // data buffer A
    float ab0, ab1, ab2, ab3;  int pb0, pb1, pb2, pb3;   // data buffer B

#define AGG_LDI(eb_, j0, j1, j2, j3) do { \
        j0 = ep[min((eb_), dm1)];     j1 = ep[min((eb_) + 1, dm1)]; \
        j2 = ep[min((eb_) + 2, dm1)]; j3 = ep[min((eb_) + 3, dm1)]; } while (0)

#define AGG_LDD(j0, j1, j2, j3, a0_, a1_, a2_, a3_, q0_, q1_, q2_, q3_) do { \
        a0_ = a_src[(size_t)(j0) * 4 + h];  q0_ = *(const int*)(xp8 + (size_t)(j0) * HC + xoff); \
        a1_ = a_src[(size_t)(j1) * 4 + h];  q1_ = *(const int*)(xp8 + (size_t)(j1) * HC + xoff); \
        a2_ = a_src[(size_t)(j2) * 4 + h];  q2_ = *(const int*)(xp8 + (size_t)(j2) * HC + xoff); \
        a3_ = a_src[(size_t)(j3) * 4 + h];  q3_ = *(const int*)(xp8 + (size_t)(j3) * HC + xoff); } while (0)

#define AGG_CMP(eb_, a0_, a1_, a2_, a3_, q0_, q1_, q2_, q3_) do { \
        floatx2 za = {a0_, a1_}, zb = {a2_, a3_}; \
        za = za + adv;  zb = zb + adv;                 /* v_pk_add_f32 */ \
        floatx2 sa = za * nsv, sb = zb * nsv;          /* v_pk_mul_f32 */ \
        za = __builtin_elementwise_max(za, sa); \
        zb = __builtin_elementwise_max(zb, sb); \
        float w0 = exp2f(za.x), w1 = exp2f(za.y); \
        float w2 = exp2f(zb.x), w3 = exp2f(zb.y); \
        if ((eb_) + 3 >= deg) {               /* wave-uniform, taken only on last batch */ \
            if ((eb_) + 1 >= deg) w1 = 0.f; \
            if ((eb_) + 2 >= deg) w2 = 0.f; \
            if ((eb_) + 3 >= deg) w3 = 0.f; \
        } \
        den += (w0 + w1) + (w2 + w3); \
        floatx4 v0 = dec4(q0_), v1 = dec4(q1_), v2 = dec4(q2_), v3 = dec4(q3_); \
        floatx2 w0v = {w0, w0}, w1v = {w1, w1}, w2v = {w2, w2}, w3v = {w3, w3}; \
        acc01 = __builtin_elementwise_fma(w0v, (floatx2){v0.x, v0.y}, acc01); \
        acc23 = __builtin_elementwise_fma(w0v, (floatx2){v0.z, v0.w}, acc23); \
        acc01 = __builtin_elementwise_fma(w1v, (floatx2){v1.x, v1.y}, acc01); \
        acc23 = __builtin_elementwise_fma(w1v, (floatx2){v1.z, v1.w}, acc23); \
        acc01 = __builtin_elementwise_fma(w2v, (floatx2){v2.x, v2.y}, acc01); \
        acc23 = __builtin_elementwise_fma(w2v, (floatx2){v2.z, v2.w}, acc23); \
        acc01 = __builtin_elementwise_fma(w3v, (floatx2){v3.x, v3.y}, acc01); \
        acc23 = __builtin_elementwise_fma(w3v, (floatx2){v3.z, v3.w}, acc23); } while (0)

    // prologue: batch 0 idx + data, batch 1 idx
    AGG_LDI(0, iA0, iA1, iA2, iA3);
    AGG_LDD(iA0, iA1, iA2, iA3, aa0, aa1, aa2, aa3, pa0, pa1, pa2, pa3);
    if (nb > 1) AGG_LDI(4, iB0, iB1, iB2, iB3);

    for (int b = 0; b < nb; b += 2) {
        int eb = b * 4;
        // even slot: data(b+1)->bufB first (its idx is old), then idx(b+2)->iA
        if (b + 1 < nb) AGG_LDD(iB0, iB1, iB2, iB3, ab0, ab1, ab2, ab3, pb0, pb1, pb2, pb3);
        if (b + 2 < nb) AGG_LDI(eb + 8, iA0, iA1, iA2, iA3);
        AGG_CMP(eb, aa0, aa1, aa2, aa3, pa0, pa1, pa2, pa3);
        if (b + 1 < nb) {
            // odd slot
            if (b + 2 < nb) AGG_LDD(iA0, iA1, iA2, iA3, aa0, aa1, aa2, aa3, pa0, pa1, pa2, pa3);
            if (b + 3 < nb) AGG_LDI(eb + 12, iB0, iB1, iB2, iB3);
            AGG_CMP(eb + 4, ab0, ab1, ab2, ab3, pb0, pb1, pb2, pb3);
        }
    }

#undef AGG_LDI
#undef AGG_LDD
#undef AGG_CMP

    float r = 1.f / den;
    float acc0 = acc01.x * r, acc1 = acc01.y * r;
    float acc2 = acc23.x * r, acc3 = acc23.y * r;
#pragma unroll
    for (int m = 16; m <= 32; m <<= 1) {
        acc0 += __shfl_xor(acc0, m, 64);
        acc1 += __shfl_xor(acc1, m, 64);
        acc2 += __shfl_xor(acc2, m, 64);
        acc3 += __shfl_xor(acc3, m, 64);
    }
    if (lane < 16) {
        const float* bp = bias + lane * 4;
        float4 o;
        o.x = fmaxf(0.25f * acc0 + bp[0], 0.f);
        o.y = fmaxf(0.25f * acc1 + bp[1], 0.f);
        o.z = fmaxf(0.25f * acc2 + bp[2], 0.f);
        o.w = fmaxf(0.25f * acc3 + bp[3], 0.f);
        *(float4*)&hbuf[(size_t)n * CC + lane * 4] = o;
    }
}

// ---------------------------------------------------------------------------
// Fused mean-pool + MLP head: one block per graph. batch is sorted, so each
// graph's node range comes from two binary searches; 4 waves stride the rows
// (coalesced 256B row reads, 4-deep independent), LDS-reduce, wave 0 runs
// the MLP. Replaces pool1 (atomics over 25.6 MB) + pool2 + gsum/gcnt bufs.
// ---------------------------------------------------------------------------
__global__ __launch_bounds__(256) void pool_kernel(
    const float* __restrict__ hbuf, const int* __restrict__ batch,
    const float* __restrict__ w1, const float* __restrict__ b1,
    const float* __restrict__ w2, const float* __restrict__ b2,
    float* __restrict__ out)
{
    __shared__ float part[4][64];
    __shared__ float gv[64];

    const int g = blockIdx.x;
    const int lane = threadIdx.x & 63;
    const int w = threadIdx.x >> 6;

    // lower_bound(batch, g) / lower_bound(batch, g+1)
    int lo = 0, hi = N_NODES;
    while (lo < hi) { int m = (lo + hi) >> 1; if (batch[m] < g) lo = m + 1; else hi = m; }
    const int start = lo;
    hi = N_NODES;
    while (lo < hi) { int m = (lo + hi) >> 1; if (batch[m] < g + 1) lo = m + 1; else hi = m; }
    const int end = lo;
    const int cnt = end - start;

    // 4-deep unrolled row accumulation (independent loads in flight)
    float s0 = 0.f, s1 = 0.f, s2 = 0.f, s3 = 0.f;
    int r = start + w;
    for (; r + 12 < end; r += 16) {
        s0 += hbuf[(size_t)r * CC + lane];
        s1 += hbuf[(size_t)(r + 4) * CC + lane];
        s2 += hbuf[(size_t)(r + 8) * CC + lane];
        s3 += hbuf[(size_t)(r + 12) * CC + lane];
    }
    for (; r < end; r += 4) s0 += hbuf[(size_t)r * CC + lane];
    part[w][lane] = (s0 + s1) + (s2 + s3);
    __syncthreads();

    if (threadIdx.x < 64) {
        float t = (part[0][lane] + part[1][lane]) + (part[2][lane] + part[3][lane]);
        gv[lane] = t / (float)max(cnt, 1);
    }
    __syncthreads();

    if (w == 0) {
        float hid = b1[lane];
        for (int c = 0; c < 64; c++) hid = fmaf(gv[c], w1[c * 64 + lane], hid);
        hid = fmaxf(hid, 0.f);
        float p = hid * w2[lane];
#pragma unroll
        for (int off = 32; off > 0; off >>= 1) p += __shfl_xor(p, off, 64);
        if (lane == 0) out[g] = 1.f / (1.f + __expf(-(p + b2[0])));
    }
}

// ---------------------------------------------------------------------------
extern "C" void kernel_launch(void* const* d_in, const int* in_sizes, int n_in,
                              void* d_out, int out_size, void* d_ws, size_t ws_size,
                              hipStream_t stream)
{
    const float* x       = (const float*)d_in[0];
    const float* W       = (const float*)d_in[1];
    const float* att_src = (const float*)d_in[2];
    const float* att_dst = (const float*)d_in[3];
    const float* bias    = (const float*)d_in[4];
    const float* w1      = (const float*)d_in[5];
    const float* b1      = (const float*)d_in[6];
    const float* w2      = (const float*)d_in[7];
    const float* b2      = (const float*)d_in[8];
    const int*   ei      = (const int*)d_in[9];
    const int*   batch   = (const int*)d_in[10];
    float* out = (float*)d_out;

    char* ws = (char*)d_ws;
    size_t off = 0;
    auto alloc = [&](size_t bytes) -> void* {
        void* p = ws + off;
        off += (bytes + 255) & ~(size_t)255;
        return p;
    };
    u16*   WbT       = (u16*)alloc((size_t)HC * K_PAD * 2);             // 196 KB
    u8*    xp8       = (u8*)alloc((size_t)N_NODES * HC);                // 25.6 MB
    float* a_src_b   = (float*)alloc((size_t)N_NODES * NH * 4);
    float* a_dst_b   = (float*)alloc((size_t)N_NODES * NH * 4);
    size_t zoff0 = off;
    int*   bcur      = (int*)alloc((size_t)NBUCK * 4);                  // zeroed
    size_t zbytes = off - zoff0;
    int2*  bins      = (int2*)alloc((size_t)NBUCK * BCAP * 8);          // 16.1 MB
    int2*  rs_deg    = (int2*)alloc((size_t)N_NODES * 8);               // 800 KB
    int*   csr       = (int*)alloc((size_t)NBUCK * BCAP * 4);           // 8 MB
    float* hbuf      = (float*)alloc((size_t)N_NODES * CC * 4);         // 25.6 MB

    hipMemsetAsync(bcur, 0, zbytes, stream);

    convw_kernel<<<(HC * 96 + 255) / 256, 256, 0, stream>>>(W, WbT);

    gemm_bin_kernel<<<BIN_BLOCKS + GEMM_BLOCKS, 512, 0, stream>>>(
        x, WbT, xp8, att_src, att_dst, a_src_b, a_dst_b, ei, bcur, bins);

    fill3_kernel<<<NBUCK, 512, 0, stream>>>(bcur, bins, rs_deg, csr);

    aggregate_kernel<<<(N_NODES + 3) / 4, 256, 0, stream>>>(xp8, a_src_b, a_dst_b,
                                                            rs_deg, csr, bias, hbuf);

    pool_kernel<<<N_GRAPHS, 256, 0, stream>>>(hbuf, batch, w1, b1, w2, b2, out);
}